// Round 11
// baseline (128.913 us; speedup 1.0000x reference)
//
#include <hip/hip_runtime.h>
#include <hip/hip_bf16.h>

typedef __attribute__((ext_vector_type(4))) float f32x4;
typedef __attribute__((ext_vector_type(8))) short s16x8;
typedef __attribute__((ext_vector_type(2))) unsigned int u32x2;
typedef __attribute__((ext_vector_type(4))) unsigned int u32x4;
typedef unsigned short u16;
typedef unsigned int u32;

#define MTOT 16384
// scale * log2(e): scores come out pre-multiplied for v_exp_f32 (2^x)
#define QSCALE 0.34004649151f

__device__ __forceinline__ u16 f2bf(float f){
  u32 u = __builtin_bit_cast(u32, f);
  u = (u + 0x7fffu + ((u >> 16) & 1u)) >> 16;
  return (u16)u;
}
__device__ __forceinline__ float bf2f(u16 u){
  u32 x = ((u32)u) << 16;
  return __builtin_bit_cast(float, x);
}
__device__ __forceinline__ float bfu32lo(u32 w){ return __builtin_bit_cast(float, (u32)(w << 16)); }
__device__ __forceinline__ float bfu32hi(u32 w){ return __builtin_bit_cast(float, (u32)(w & 0xffff0000u)); }
__device__ __forceinline__ u32 cvtpk(float lo, float hi){
  u32 r;
  asm("v_cvt_pk_bf16_f32 %0, %1, %2" : "=v"(r) : "v"(lo), "v"(hi));
  return r;
}
// raw 2^x (Q pre-scaled by log2e): single v_exp_f32, no libm wrapper
__device__ __forceinline__ float fexp2(float x){
  float r;
  asm("v_exp_f32 %0, %1" : "=v"(r) : "v"(x));
  return r;
}

// ---------------- merged head: patches+LN1 (blocks 0..511) | weight prep (512..1366)
__global__ __launch_bounds__(256) void head_k(
    const float* __restrict__ x, const float* __restrict__ g, const float* __restrict__ b_,
    u16* __restrict__ tb, u16* __restrict__ ln1,
    const float* __restrict__ rw, const float* __restrict__ qw,
    const float* __restrict__ pw, const float* __restrict__ f1, const float* __restrict__ f2,
    u16* __restrict__ WcT, u16* __restrict__ pwT, u16* __restrict__ f1wT, u16* __restrict__ f2wT)
{
  __shared__ float lds_t[32][296];
  __shared__ float red_s[8][32];
  __shared__ float red_q[8][32];
  __shared__ float smu[32], srs[32];
  int bid = blockIdx.x;
  int tid = threadIdx.x;
  if (bid >= 512){
    // ------- weight prep branch -------
    int idx = (bid - 512) * 256 + tid;
    const int N1 = 288*432, N2 = 288*160, N3 = 72*288;
    if (idx < N1){
      int i = idx / 432, j = idx - i * 432;   // i ~ wave-uniform: rw broadcast, qw coalesced
      float acc = 0.f;
      for (int k = 0; k < 144; ++k) acc += rw[i*144 + k] * qw[k*432 + j];
      WcT[j*288 + i] = f2bf(acc);
    } else if (idx < N1 + N2){
      int t = idx - N1; int n = t / 160, k = t - n * 160;
      pwT[t] = (k < 144) ? f2bf(pw[k*288 + n]) : (u16)0;
    } else if (idx < N1 + N2 + N3){
      int t = idx - (N1 + N2); int n = t / 288, k = t - n * 288;
      f1wT[t] = f2bf(f1[k*72 + n]);
    } else {
      int t = idx - (N1 + N2 + N3); int n = t / 96, k = t - n * 96;
      f2wT[t] = (k < 72) ? f2bf(f2[k*288 + n]) : (u16)0;
    }
    return;
  }
  // ------- patches + LN1 branch -------
  int b = bid >> 7, i = (bid >> 1) & 63, j0 = (bid & 1) * 32;
  int q = tid >> 5;
  int jl = tid & 31;
  int j = j0 + jl;
  const float* xb = x + ((long)b * 32) * 4096;
  float s = 0.f, ss = 0.f;
#pragma unroll
  for (int c4 = 0; c4 < 4; ++c4){
    int c = q * 4 + c4;
    const float* xc = xb + c * 4096;
#pragma unroll
    for (int di = 0; di < 3; ++di){
      int ii = i + di - 1;
      bool iok = (ii >= 0) && (ii < 64);
#pragma unroll
      for (int dj = 0; dj < 3; ++dj){
        int jj = j + dj - 1;
        float v = 0.f;
        if (iok && jj >= 0 && jj < 64) v = xc[ii * 64 + jj];
        lds_t[jl][c * 9 + di * 3 + dj] = v;
        s += v; ss += v * v;
      }
    }
  }
  red_s[q][jl] = s; red_q[q][jl] = ss;
  __syncthreads();
  if (q == 0){
    float S = 0.f, SS = 0.f;
#pragma unroll
    for (int k = 0; k < 8; ++k){ S += red_s[k][jl]; SS += red_q[k][jl]; }
    float mu = S * (1.f/288.f);
    float var = SS * (1.f/288.f) - mu * mu;
    smu[jl] = mu;
    srs[jl] = rsqrtf(var + 1e-5f);
  }
  __syncthreads();
  long rowbase = ((long)b * 4096 + i * 64 + j0) * 288;
  for (int it = 0; it < 9; ++it){
    int idx = tid + it * 256;
    int p = idx / 72;
    int kk = idx - p * 72;
    f32x4 v = *(f32x4*)&lds_t[p][kk * 4];
    long base = rowbase + (long)p * 288 + kk * 4;
    u32x2 pt;
    pt[0] = (u32)f2bf(v[0]) | ((u32)f2bf(v[1]) << 16);
    pt[1] = (u32)f2bf(v[2]) | ((u32)f2bf(v[3]) << 16);
    *(u32x2*)&tb[base] = pt;
    float mu = smu[p], rs = srs[p];
    u16 o0 = f2bf((v[0]-mu)*rs*g[kk*4+0] + b_[kk*4+0]);
    u16 o1 = f2bf((v[1]-mu)*rs*g[kk*4+1] + b_[kk*4+1]);
    u16 o2 = f2bf((v[2]-mu)*rs*g[kk*4+2] + b_[kk*4+2]);
    u16 o3 = f2bf((v[3]-mu)*rs*g[kk*4+3] + b_[kk*4+3]);
    u32x2 pk;
    pk[0] = (u32)o0 | ((u32)o1 << 16);
    pk[1] = (u32)o2 | ((u32)o3 << 16);
    *(u32x2*)&ln1[base] = pk;
  }
}

// ---------------- generic MFMA GEMM: C[M,N] = A[M,K](bf16) @ BT[N][KP](bf16) ----
// MODE 0: qkv scatter into Q/K [bch][1024][32] + V [bch][seg][32][256]; writes
//         Q-pads (d 18..31 = 0) and V ones-row (d=18 = 1.0) as part of epilogue.
// MODE 1: proj: +bias, +res(bf16), out bf16
template<int MODE, int KP, int MR>
__global__ __launch_bounds__(256) void gemm_k(
    const u16* __restrict__ A, const u16* __restrict__ BT,
    const float* __restrict__ bias, const void* __restrict__ resp,
    void* __restrict__ out0, void* __restrict__ out1, void* __restrict__ out2,
    int M, int N, int K)
{
  __shared__ u16 As[MR][KP + 8];
  __shared__ u16 Bs[64][KP + 8];
  const int nseg = KP >> 3;
  int tid = threadIdx.x;
  int m0 = blockIdx.x * MR, n0 = blockIdx.y * 64;
  for (int idx = tid; idx < (MR + 64) * nseg; idx += 256){
    int r = idx / nseg, sg = idx - r * nseg;
    if (r < MR){
      s16x8 v = {0,0,0,0,0,0,0,0};
      if (sg * 8 < K) v = *(const s16x8*)(A + (long)(m0 + r) * K + sg * 8);
      *(s16x8*)&As[r][sg * 8] = v;
    } else {
      int rb = r - MR;
      s16x8 w = {0,0,0,0,0,0,0,0};
      if (n0 + rb < N) w = *(const s16x8*)(BT + (long)(n0 + rb) * KP + sg * 8);
      *(s16x8*)&Bs[rb][sg * 8] = w;
    }
  }
  __syncthreads();
  int wv = tid >> 6, l = tid & 63;
  int lq = l & 15, lg = l >> 4;

#define EPI(ACC, MROW, NCOL) {                                           \
    int mrow = (MROW);                                                   \
    int ncol = (NCOL);                                                   \
    if (ncol < N){                                                       \
      if (MODE == 0){                                                    \
        int which = ncol / 144;                                          \
        int rem = ncol - which * 144;                                    \
        int hh = rem / 18;                                               \
        int dd = rem - hh * 18;                                          \
        _Pragma("unroll")                                                \
        for (int e = 0; e < 4; ++e){                                     \
          int row = mrow + e;                                            \
          long bch = (long)((row >> 10) * 8 + hh);                       \
          int kk = row & 1023;                                           \
          float v = ACC[e];                                              \
          if (which == 0){                                               \
            ((u16*)out0)[(bch<<15) + kk*32 + dd] = f2bf(v * QSCALE);     \
            if (dd < 14) ((u16*)out0)[(bch<<15) + kk*32 + 18 + dd] = (u16)0; \
          } else if (which == 1){                                        \
            int cp = (dd >> 3) ^ ((kk >> 1) & 3);                        \
            ((u16*)out1)[(bch<<15) + kk*32 + (cp<<3) + (dd&7)] = f2bf(v);\
          } else {                                                       \
            int seg = kk >> 8, jg = (kk >> 3) & 31, jp = jg ^ (dd & 7);  \
            ((u16*)out2)[(bch<<15) + seg*8192 + dd*256 + (jp<<3) + (kk&7)] = f2bf(v); \
            if (dd == 0){                                                \
              int jp1 = jg ^ 2;                                          \
              ((u16*)out2)[(bch<<15) + seg*8192 + 18*256 + (jp1<<3) + (kk&7)] = (u16)0x3F80; \
            }                                                            \
          }                                                              \
        }                                                                \
      } else {                                                           \
        float bv = bias[ncol];                                           \
        _Pragma("unroll")                                                \
        for (int e = 0; e < 4; ++e){                                     \
          long off = (long)(mrow + e) * N + ncol;                        \
          float v = ACC[e] + bv;                                         \
          if (MODE == 1){ v += bf2f(((const u16*)resp)[off]); ((u16*)out0)[off] = f2bf(v); } \
        }                                                                \
      }                                                                  \
    }                                                                    \
  }

  if constexpr (MR == 64){
    int wr = wv >> 1, wc = wv & 1;
    f32x4 acc00={0,0,0,0}, acc01={0,0,0,0}, acc10={0,0,0,0}, acc11={0,0,0,0};
    for (int kt = 0; kt < KP; kt += 32){
      s16x8 a0 = *(const s16x8*)&As[wr*32 + lq][kt + lg*8];
      s16x8 a1 = *(const s16x8*)&As[wr*32 + 16 + lq][kt + lg*8];
      s16x8 b0 = *(const s16x8*)&Bs[wc*32 + lq][kt + lg*8];
      s16x8 b1 = *(const s16x8*)&Bs[wc*32 + 16 + lq][kt + lg*8];
      acc00 = __builtin_amdgcn_mfma_f32_16x16x32_bf16(a0, b0, acc00, 0, 0, 0);
      acc01 = __builtin_amdgcn_mfma_f32_16x16x32_bf16(a0, b1, acc01, 0, 0, 0);
      acc10 = __builtin_amdgcn_mfma_f32_16x16x32_bf16(a1, b0, acc10, 0, 0, 0);
      acc11 = __builtin_amdgcn_mfma_f32_16x16x32_bf16(a1, b1, acc11, 0, 0, 0);
    }
    EPI(acc00, m0 + wr*32 + 0*16 + lg*4, n0 + wc*32 + 0*16 + lq)
    EPI(acc01, m0 + wr*32 + 0*16 + lg*4, n0 + wc*32 + 1*16 + lq)
    EPI(acc10, m0 + wr*32 + 1*16 + lg*4, n0 + wc*32 + 0*16 + lq)
    EPI(acc11, m0 + wr*32 + 1*16 + lg*4, n0 + wc*32 + 1*16 + lq)
  } else {
    f32x4 c00={0,0,0,0}, c01={0,0,0,0}, c02={0,0,0,0}, c03={0,0,0,0};
    f32x4 c10={0,0,0,0}, c11={0,0,0,0}, c12={0,0,0,0}, c13={0,0,0,0};
    for (int kt = 0; kt < KP; kt += 32){
      s16x8 a0 = *(const s16x8*)&As[wv*32 + lq][kt + lg*8];
      s16x8 a1 = *(const s16x8*)&As[wv*32 + 16 + lq][kt + lg*8];
      s16x8 b0 = *(const s16x8*)&Bs[ 0 + lq][kt + lg*8];
      s16x8 b1 = *(const s16x8*)&Bs[16 + lq][kt + lg*8];
      s16x8 b2 = *(const s16x8*)&Bs[32 + lq][kt + lg*8];
      s16x8 b3 = *(const s16x8*)&Bs[48 + lq][kt + lg*8];
      c00 = __builtin_amdgcn_mfma_f32_16x16x32_bf16(a0, b0, c00, 0, 0, 0);
      c01 = __builtin_amdgcn_mfma_f32_16x16x32_bf16(a0, b1, c01, 0, 0, 0);
      c02 = __builtin_amdgcn_mfma_f32_16x16x32_bf16(a0, b2, c02, 0, 0, 0);
      c03 = __builtin_amdgcn_mfma_f32_16x16x32_bf16(a0, b3, c03, 0, 0, 0);
      c10 = __builtin_amdgcn_mfma_f32_16x16x32_bf16(a1, b0, c10, 0, 0, 0);
      c11 = __builtin_amdgcn_mfma_f32_16x16x32_bf16(a1, b1, c11, 0, 0, 0);
      c12 = __builtin_amdgcn_mfma_f32_16x16x32_bf16(a1, b2, c12, 0, 0, 0);
      c13 = __builtin_amdgcn_mfma_f32_16x16x32_bf16(a1, b3, c13, 0, 0, 0);
    }
    EPI(c00, m0 + wv*32 + lg*4,      n0 +  0 + lq)
    EPI(c01, m0 + wv*32 + lg*4,      n0 + 16 + lq)
    EPI(c02, m0 + wv*32 + lg*4,      n0 + 32 + lq)
    EPI(c03, m0 + wv*32 + lg*4,      n0 + 48 + lq)
    EPI(c10, m0 + wv*32 + 16 + lg*4, n0 +  0 + lq)
    EPI(c11, m0 + wv*32 + 16 + lg*4, n0 + 16 + lq)
    EPI(c12, m0 + wv*32 + 16 + lg*4, n0 + 32 + lq)
    EPI(c13, m0 + wv*32 + 16 + lg*4, n0 + 48 + lq)
  }
#undef EPI
}

// ---------------- fused chunked attention (k-split partials) --------------------
// grid 1024: bid = kh*512 + qt*128 + bch (bid%8 = h keeps panel/XCD affinity).
// Each block: 64 q-rows/wave x 512 k (2 of 4 segments, chosen by kh).
// Writes UNNORMALIZED partial O (bf16) and partial L (f32); comb_k normalizes.
__global__ __launch_bounds__(256) void attn_k(
    const u16* __restrict__ Qp, const u16* __restrict__ Kpp,
    const u16* __restrict__ Vt, u16* __restrict__ paoO0, u16* __restrict__ paoO1,
    float* __restrict__ paoL)
{
  __shared__ u16 Ks[8192];
  __shared__ u16 Vs[8192];
  int bid = blockIdx.x;
  int kh = bid >> 9;
  int r2 = bid & 511;
  int qt = r2 >> 7, bch = r2 & 127;
  int b = bch >> 5, c = (bch >> 3) & 3, h = bch & 7;
  int tid = threadIdx.x, wv = tid >> 6, l = tid & 63;
  int lq = l & 15, lg = l >> 4;
  long base = (long)bch << 15;
  int q0 = qt * 256 + wv * 64 + lq;
  s16x8 qf0 = *(const s16x8*)(Qp + base + (long)(q0     ) * 32 + lg * 8);
  s16x8 qf1 = *(const s16x8*)(Qp + base + (long)(q0 + 16) * 32 + lg * 8);
  s16x8 qf2 = *(const s16x8*)(Qp + base + (long)(q0 + 32) * 32 + lg * 8);
  s16x8 qf3 = *(const s16x8*)(Qp + base + (long)(q0 + 48) * 32 + lg * 8);
  f32x4 oA0={0,0,0,0}, oA1={0,0,0,0}, oA2={0,0,0,0}, oA3={0,0,0,0};
  f32x4 oB0={0,0,0,0}, oB1={0,0,0,0}, oB2={0,0,0,0}, oB3={0,0,0,0};
  const f32x4 zf = {0,0,0,0};
  const u16* kg = Kpp + base + kh * 16384;   // this half's 2 segments
  const u16* vg = Vt  + base + kh * 16384;
  u32x4 kr[4], vr[4];
#pragma unroll
  for (int r = 0; r < 4; ++r){
    kr[r] = *(const u32x4*)(kg + (r*256 + tid) * 8);
    vr[r] = *(const u32x4*)(vg + (r*256 + tid) * 8);
  }
  int kswz = (lq >> 1) & 3;
  int vswz = lq & 7;
  int ho = (lg & 1) << 2;         // half-granule offset (u16 units)
  int gl = lg >> 1;               // granule sub-index
  for (int sg2 = 0; sg2 < 2; ++sg2){
    __syncthreads();
#pragma unroll
    for (int r = 0; r < 4; ++r){
      *(u32x4*)&Ks[(r*256 + tid) * 8] = kr[r];
      *(u32x4*)&Vs[(r*256 + tid) * 8] = vr[r];
    }
    __syncthreads();
    if (sg2 == 0){
      const u16* kgn = kg + 8192;
      const u16* vgn = vg + 8192;
#pragma unroll
      for (int r = 0; r < 4; ++r){
        kr[r] = *(const u32x4*)(kgn + (r*256 + tid) * 8);
        vr[r] = *(const u32x4*)(vgn + (r*256 + tid) * 8);
      }
    }
#pragma unroll 2
    for (int t32 = 0; t32 < 8; ++t32){
      int k0 = t32 * 32;
      int r0 = k0 + lq, r1 = k0 + 16 + lq;
      s16x8 kf0 = *(const s16x8*)&Ks[r0*32 + ((lg ^ kswz) << 3)];
      s16x8 kf1 = *(const s16x8*)&Ks[r1*32 + ((lg ^ kswz) << 3)];
      f32x4 s00 = __builtin_amdgcn_mfma_f32_16x16x32_bf16(kf0, qf0, zf, 0, 0, 0);
      f32x4 s01 = __builtin_amdgcn_mfma_f32_16x16x32_bf16(kf0, qf1, zf, 0, 0, 0);
      f32x4 s02 = __builtin_amdgcn_mfma_f32_16x16x32_bf16(kf0, qf2, zf, 0, 0, 0);
      f32x4 s03 = __builtin_amdgcn_mfma_f32_16x16x32_bf16(kf0, qf3, zf, 0, 0, 0);
      f32x4 s10 = __builtin_amdgcn_mfma_f32_16x16x32_bf16(kf1, qf0, zf, 0, 0, 0);
      f32x4 s11 = __builtin_amdgcn_mfma_f32_16x16x32_bf16(kf1, qf1, zf, 0, 0, 0);
      f32x4 s12 = __builtin_amdgcn_mfma_f32_16x16x32_bf16(kf1, qf2, zf, 0, 0, 0);
      f32x4 s13 = __builtin_amdgcn_mfma_f32_16x16x32_bf16(kf1, qf3, zf, 0, 0, 0);
      s16x8 pb0, pb1, pb2, pb3;
      {
        u32x4 w0, w1, w2, w3;
        w0[0] = cvtpk(fexp2(s00[0]), fexp2(s00[1]));
        w0[1] = cvtpk(fexp2(s00[2]), fexp2(s00[3]));
        w0[2] = cvtpk(fexp2(s10[0]), fexp2(s10[1]));
        w0[3] = cvtpk(fexp2(s10[2]), fexp2(s10[3]));
        w1[0] = cvtpk(fexp2(s01[0]), fexp2(s01[1]));
        w1[1] = cvtpk(fexp2(s01[2]), fexp2(s01[3]));
        w1[2] = cvtpk(fexp2(s11[0]), fexp2(s11[1]));
        w1[3] = cvtpk(fexp2(s11[2]), fexp2(s11[3]));
        w2[0] = cvtpk(fexp2(s02[0]), fexp2(s02[1]));
        w2[1] = cvtpk(fexp2(s02[2]), fexp2(s02[3]));
        w2[2] = cvtpk(fexp2(s12[0]), fexp2(s12[1]));
        w2[3] = cvtpk(fexp2(s12[2]), fexp2(s12[3]));
        w3[0] = cvtpk(fexp2(s03[0]), fexp2(s03[1]));
        w3[1] = cvtpk(fexp2(s03[2]), fexp2(s03[3]));
        w3[2] = cvtpk(fexp2(s13[0]), fexp2(s13[1]));
        w3[3] = cvtpk(fexp2(s13[2]), fexp2(s13[3]));
        pb0 = __builtin_bit_cast(s16x8, w0);
        pb1 = __builtin_bit_cast(s16x8, w1);
        pb2 = __builtin_bit_cast(s16x8, w2);
        pb3 = __builtin_bit_cast(s16x8, w3);
      }
      // sigma split-read: slots 8lg+{0..3} <- k0+4lg+{0..3}; +{4..7} <- k0+16+4lg+{0..3}
      int G1 = (k0 >> 3) + gl;
      int a_lo = lq*256 + ((G1 ^ vswz) << 3) + ho;
      int a_hi = lq*256 + (((G1 + 2) ^ vswz) << 3) + ho;
      u32x2 vl0 = *(const u32x2*)&Vs[a_lo];
      u32x2 vh0 = *(const u32x2*)&Vs[a_hi];
      u32x2 vl1 = *(const u32x2*)&Vs[a_lo + 4096];
      u32x2 vh1 = *(const u32x2*)&Vs[a_hi + 4096];
      u32x4 vc0; vc0[0] = vl0[0]; vc0[1] = vl0[1]; vc0[2] = vh0[0]; vc0[3] = vh0[1];
      u32x4 vc1; vc1[0] = vl1[0]; vc1[1] = vl1[1]; vc1[2] = vh1[0]; vc1[3] = vh1[1];
      s16x8 va = __builtin_bit_cast(s16x8, vc0);
      s16x8 vb = __builtin_bit_cast(s16x8, vc1);
      oA0 = __builtin_amdgcn_mfma_f32_16x16x32_bf16(va, pb0, oA0, 0, 0, 0);
      oA1 = __builtin_amdgcn_mfma_f32_16x16x32_bf16(va, pb1, oA1, 0, 0, 0);
      oA2 = __builtin_amdgcn_mfma_f32_16x16x32_bf16(va, pb2, oA2, 0, 0, 0);
      oA3 = __builtin_amdgcn_mfma_f32_16x16x32_bf16(va, pb3, oA3, 0, 0, 0);
      oB0 = __builtin_amdgcn_mfma_f32_16x16x32_bf16(vb, pb0, oB0, 0, 0, 0);
      oB1 = __builtin_amdgcn_mfma_f32_16x16x32_bf16(vb, pb1, oB1, 0, 0, 0);
      oB2 = __builtin_amdgcn_mfma_f32_16x16x32_bf16(vb, pb2, oB2, 0, 0, 0);
      oB3 = __builtin_amdgcn_mfma_f32_16x16x32_bf16(vb, pb3, oB3, 0, 0, 0);
    }
  }
  long cn = (long)b * 4096 + c * 1024;
  u16* po = kh ? paoO1 : paoO0;
  float* pl = paoL + (long)kh * 131072;     // [kh][16384][8]
  // L (partial) = oB[2] of lanes lg==0 (V ones row at d=18)
#define OUTJ(J, OA, OB) {                                                \
    long row = cn + q0 + 16*(J);                                         \
    long ob = row * 144 + h * 18;                                        \
    _Pragma("unroll")                                                    \
    for (int e = 0; e < 4; ++e)                                          \
      po[ob + lg * 4 + e] = f2bf(OA[e]);                                 \
    if (lg == 0){                                                        \
      po[ob + 16] = f2bf(OB[0]);                                         \
      po[ob + 17] = f2bf(OB[1]);                                         \
      pl[row * 8 + h] = OB[2];                                           \
    }                                                                    \
  }
  OUTJ(0, oA0, oB0)
  OUTJ(1, oA1, oB1)
  OUTJ(2, oA2, oB2)
  OUTJ(3, oA3, oB3)
#undef OUTJ
}

// ---------------- combine: aob = (O0 + O1) / (L0 + L1) --------------------------
// In-place over paoO0 (each thread reads its 16B then overwrites the same 16B).
__global__ __launch_bounds__(256) void comb_k(
    u16* __restrict__ o0, const u16* __restrict__ o1, const float* __restrict__ paoL)
{
  int idx = blockIdx.x * 256 + threadIdx.x;    // row*18 + sg; 16384*18 total
  int row = idx / 18, sg = idx - row * 18;
  const float* l0 = paoL + (long)row * 8;
  const float* l1 = paoL + 131072 + (long)row * 8;
  long off = (long)row * 144 + sg * 8;
  u32x4 a = *(const u32x4*)(o0 + off);
  u32x4 b = *(const u32x4*)(o1 + off);
  int c0 = sg * 8;
  u32x4 res;
#pragma unroll
  for (int w = 0; w < 4; ++w){
    int cl = c0 + w*2, ch = cl + 1;
    int hl = cl / 18, hh = ch / 18;
    float rLl = 1.f / (l0[hl] + l1[hl]);
    float rLh = 1.f / (l0[hh] + l1[hh]);
    float sl = (bfu32lo(a[w]) + bfu32lo(b[w])) * rLl;
    float sh = (bfu32hi(a[w]) + bfu32hi(b[w])) * rLh;
    res[w] = (u32)f2bf(sl) | ((u32)f2bf(sh) << 16);
  }
  *(u32x4*)(o0 + off) = res;
}

// ---------------- fused LN2 + fc1(relu) + fc2 + residual ------------------------
// 4 waves per block, 64 rows; each wave owns 16 rows.
__global__ __launch_bounds__(256) void mlp_k(
    const u16* __restrict__ t2, const float* __restrict__ g, const float* __restrict__ b_,
    const u16* __restrict__ f1wT, const float* __restrict__ f1b,
    const u16* __restrict__ f2wT, const float* __restrict__ f2b,
    float* __restrict__ out)
{
  __shared__ u16 T2s[64][296];
  __shared__ u16 H1s[64][104];
  __shared__ float smu[64], srs[64];
  int tid = threadIdx.x;
  int wv = tid >> 6, l = tid & 63;
  int lq = l & 15, lg = l >> 4;
  long row0 = (long)blockIdx.x * 64;
  for (int idx = tid; idx < 64*36; idx += 256){
    int r = idx / 36, sg = idx - r*36;
    *(s16x8*)&T2s[r][sg*8] = *(const s16x8*)(t2 + (row0 + r)*288 + sg*8);
  }
  for (int idx = tid; idx < 64*16; idx += 256){
    int r = idx >> 4, c2 = idx & 15;
    *(u32*)&H1s[r][72 + c2*2] = 0u;
  }
  __syncthreads();
  {
    int r = tid >> 2, qt = tid & 3;
    const u16* pr = &T2s[r][qt*72];
    float s = 0.f, ss = 0.f;
#pragma unroll 4
    for (int i = 0; i < 36; ++i){
      u32 w = *(const u32*)(pr + i*2);
      float a = bfu32lo(w), c = bfu32hi(w);
      s += a + c; ss += a*a + c*c;
    }
    s  += __shfl_xor(s, 1, 64);  s  += __shfl_xor(s, 2, 64);
    ss += __shfl_xor(ss, 1, 64); ss += __shfl_xor(ss, 2, 64);
    if (qt == 0){
      float mu = s * (1.f/288.f);
      float var = ss * (1.f/288.f) - mu*mu;
      smu[r] = mu; srs[r] = rsqrtf(var + 1e-5f);
    }
  }
  __syncthreads();
  int myrow = wv*16 + lq;
  float mu = smu[myrow], rs = srs[myrow];
  f32x4 a0={0,0,0,0}, a1={0,0,0,0}, a2={0,0,0,0}, a3={0,0,0,0}, a4={0,0,0,0};
  int n4c = (lq < 8) ? (64 + lq) : 71;   // clamp; cols >=72 discarded
#pragma unroll
  for (int kt = 0; kt < 9; ++kt){
    s16x8 raw = *(const s16x8*)&T2s[myrow][kt*32 + lg*8];
    f32x4 g0 = *(const f32x4*)(g  + kt*32 + lg*8);
    f32x4 g1 = *(const f32x4*)(g  + kt*32 + lg*8 + 4);
    f32x4 b0 = *(const f32x4*)(b_ + kt*32 + lg*8);
    f32x4 b1 = *(const f32x4*)(b_ + kt*32 + lg*8 + 4);
    s16x8 af;
#pragma unroll
    for (int i = 0; i < 4; ++i){
      af[i]   = (short)f2bf((bf2f((u16)raw[i])   - mu)*rs*g0[i] + b0[i]);
      af[4+i] = (short)f2bf((bf2f((u16)raw[4+i]) - mu)*rs*g1[i] + b1[i]);
    }
    s16x8 w0 = *(const s16x8*)(f1wT + (lq     )*288 + kt*32 + lg*8);
    s16x8 w1 = *(const s16x8*)(f1wT + (16 + lq)*288 + kt*32 + lg*8);
    s16x8 w2 = *(const s16x8*)(f1wT + (32 + lq)*288 + kt*32 + lg*8);
    s16x8 w3 = *(const s16x8*)(f1wT + (48 + lq)*288 + kt*32 + lg*8);
    s16x8 w4 = *(const s16x8*)(f1wT + (n4c    )*288 + kt*32 + lg*8);
    a0 = __builtin_amdgcn_mfma_f32_16x16x32_bf16(af, w0, a0, 0, 0, 0);
    a1 = __builtin_amdgcn_mfma_f32_16x16x32_bf16(af, w1, a1, 0, 0, 0);
    a2 = __builtin_amdgcn_mfma_f32_16x16x32_bf16(af, w2, a2, 0, 0, 0);
    a3 = __builtin_amdgcn_mfma_f32_16x16x32_bf16(af, w3, a3, 0, 0, 0);
    a4 = __builtin_amdgcn_mfma_f32_16x16x32_bf16(af, w4, a4, 0, 0, 0);
  }
#define H1W(ACC, F) { int n = (F)*16 + lq; if (n < 72){ float bv = f1b[n];        \
    _Pragma("unroll") for (int e = 0; e < 4; ++e)                                 \
      H1s[wv*16 + lg*4 + e][n] = f2bf(fmaxf(ACC[e] + bv, 0.f)); } }
  H1W(a0,0) H1W(a1,1) H1W(a2,2) H1W(a3,3) H1W(a4,4)
#undef H1W
  __syncthreads();
  f32x4 c[18];
#pragma unroll
  for (int f = 0; f < 18; ++f) c[f] = (f32x4){0,0,0,0};
#pragma unroll
  for (int kt = 0; kt < 3; ++kt){
    s16x8 af = *(const s16x8*)&H1s[myrow][kt*32 + lg*8];
#pragma unroll
    for (int f = 0; f < 18; ++f){
      s16x8 wf = *(const s16x8*)(f2wT + (f*16 + lq)*96 + kt*32 + lg*8);
      c[f] = __builtin_amdgcn_mfma_f32_16x16x32_bf16(af, wf, c[f], 0, 0, 0);
    }
  }
#pragma unroll
  for (int f = 0; f < 18; ++f){
    int col = f*16 + lq;
    float bv = f2b[col];
#pragma unroll
    for (int e = 0; e < 4; ++e){
      int rl = wv*16 + lg*4 + e;
      out[(row0 + rl)*288 + col] = c[f][e] + bv + bf2f(T2s[rl][col]);
    }
  }
}

// ---------------- launch ---------------------------------------------------------
extern "C" void kernel_launch(void* const* d_in, const int* in_sizes, int n_in,
                              void* d_out, int out_size, void* d_ws, size_t ws_size,
                              hipStream_t stream)
{
  const float* x   = (const float*)d_in[0];
  const float* n1g = (const float*)d_in[1];
  const float* n1b = (const float*)d_in[2];
  const float* rw  = (const float*)d_in[3];
  const float* qw  = (const float*)d_in[4];
  const float* pw  = (const float*)d_in[5];
  const float* pb  = (const float*)d_in[6];
  const float* n2g = (const float*)d_in[7];
  const float* n2b = (const float*)d_in[8];
  const float* f1w = (const float*)d_in[9];
  const float* f1b = (const float*)d_in[10];
  const float* f2w = (const float*)d_in[11];
  const float* f2b = (const float*)d_in[12];
  char* ws = (char*)d_ws;
  u16*   tb    = (u16*)(ws + 0);            // 9437184  bf16 residual t
  u16*   ln1b  = (u16*)(ws + 9437184);      // 9437184  (dead after qkv)
  u16*   paoO0 = (u16*)(ws + 9437184);      // 4718592  partial O (kh=0); becomes aob in-place
  float* paoL  = (float*)(ws + 14155776);   // 1048576  [2][16384][8] f32 partial L
  u16*   Qp    = (u16*)(ws + 18874368);     // 8388608  [128 bch][1024][32]
  u16*   Kp    = (u16*)(ws + 27262976);     // 8388608  swizzled
  u16*   Vtp   = (u16*)(ws + 35651584);     // 8388608  [128 bch][4 seg][32 d][256] identity-k
  u16*   paoO1 = (u16*)(ws + 44040192);     // 4718592  partial O (kh=1)
  u16*   aob   = paoO0;                     // combined, normalized (in-place)
  u16*   t2    = (u16*)(ws + 18874368);     // aliases Qp (dead after attn)
  u16*   WcT   = (u16*)(ws + 48758784);     // 432*288*2 = 248832
  u16*   pwT   = (u16*)(ws + 49007616);     // 288*160*2 = 92160
  u16*   f1wT  = (u16*)(ws + 49099776);     // 72*288*2  = 41472
  u16*   f2wT  = (u16*)(ws + 49141248);     // 288*96*2  = 55296
  float* out   = (float*)d_out;

  // blocks 0..511: patches+LN1 ; 512..1366: weight prep (independent work)
  head_k<<<1367, 256, 0, stream>>>(x, n1g, n1b, tb, ln1b,
                                   rw, qw, pw, f1w, f2w, WcT, pwT, f1wT, f2wT);
  // qkv = ln1 @ Wc -> scattered into Qp/Kp/Vtp (+ Q-pad zeros, V ones row)
  gemm_k<0,288,64><<<dim3(256,7), 256, 0, stream>>>(ln1b, WcT, nullptr, nullptr, Qp, Kp, Vtp, MTOT, 432, 288);
  // attention partials over k-halves, then combine+normalize
  attn_k<<<1024, 256, 0, stream>>>(Qp, Kp, Vtp, paoO0, paoO1, paoL);
  comb_k<<<1152, 256, 0, stream>>>(paoO0, paoO1, paoL);
  // t2 = t + attn @ proj_w + proj_b  (bf16)
  gemm_k<1,160,64><<<dim3(256,5), 256, 0, stream>>>(aob, pwT, pb, tb, t2, nullptr, nullptr, MTOT, 288, 144);
  // out = t2 + relu(LN(t2) @ f1w + f1b) @ f2w + f2b   (fused, 4 waves/block)
  mlp_k<<<256, 256, 0, stream>>>(t2, n2g, n2b, f1wT, f1b, f2wT, f2b, out);
}

// Round 12
// 122.465 us; speedup vs baseline: 1.0526x; 1.0526x over previous
//
#include <hip/hip_runtime.h>
#include <hip/hip_bf16.h>

typedef __attribute__((ext_vector_type(4))) float f32x4;
typedef __attribute__((ext_vector_type(8))) short s16x8;
typedef __attribute__((ext_vector_type(2))) unsigned int u32x2;
typedef __attribute__((ext_vector_type(4))) unsigned int u32x4;
typedef unsigned short u16;
typedef unsigned int u32;

#define MTOT 16384
// scale * log2(e): scores come out pre-multiplied for v_exp_f32 (2^x)
#define QSCALE 0.34004649151f

__device__ __forceinline__ u16 f2bf(float f){
  u32 u = __builtin_bit_cast(u32, f);
  u = (u + 0x7fffu + ((u >> 16) & 1u)) >> 16;
  return (u16)u;
}
__device__ __forceinline__ float bf2f(u16 u){
  u32 x = ((u32)u) << 16;
  return __builtin_bit_cast(float, x);
}
__device__ __forceinline__ float bfu32lo(u32 w){ return __builtin_bit_cast(float, (u32)(w << 16)); }
__device__ __forceinline__ float bfu32hi(u32 w){ return __builtin_bit_cast(float, (u32)(w & 0xffff0000u)); }
__device__ __forceinline__ u32 cvtpk(float lo, float hi){
  u32 r;
  asm("v_cvt_pk_bf16_f32 %0, %1, %2" : "=v"(r) : "v"(lo), "v"(hi));
  return r;
}
// raw 2^x (Q pre-scaled by log2e): single v_exp_f32, no libm wrapper
__device__ __forceinline__ float fexp2(float x){
  float r;
  asm("v_exp_f32 %0, %1" : "=v"(r) : "v"(x));
  return r;
}

// ---------------- merged head: patches+LN1 (blocks 0..511) | weight prep (512..1366)
__global__ __launch_bounds__(256) void head_k(
    const float* __restrict__ x, const float* __restrict__ g, const float* __restrict__ b_,
    u16* __restrict__ tb, u16* __restrict__ ln1,
    const float* __restrict__ rw, const float* __restrict__ qw,
    const float* __restrict__ pw, const float* __restrict__ f1, const float* __restrict__ f2,
    u16* __restrict__ WcT, u16* __restrict__ pwT, u16* __restrict__ f1wT, u16* __restrict__ f2wT)
{
  __shared__ float lds_t[32][296];
  __shared__ float red_s[8][32];
  __shared__ float red_q[8][32];
  __shared__ float smu[32], srs[32];
  int bid = blockIdx.x;
  int tid = threadIdx.x;
  if (bid >= 512){
    // ------- weight prep branch -------
    int idx = (bid - 512) * 256 + tid;
    const int N1 = 288*432, N2 = 288*160, N3 = 72*288;
    if (idx < N1){
      int i = idx / 432, j = idx - i * 432;   // i ~ wave-uniform: rw broadcast, qw coalesced
      float acc = 0.f;
      for (int k = 0; k < 144; ++k) acc += rw[i*144 + k] * qw[k*432 + j];
      WcT[j*288 + i] = f2bf(acc);
    } else if (idx < N1 + N2){
      int t = idx - N1; int n = t / 160, k = t - n * 160;
      pwT[t] = (k < 144) ? f2bf(pw[k*288 + n]) : (u16)0;
    } else if (idx < N1 + N2 + N3){
      int t = idx - (N1 + N2); int n = t / 288, k = t - n * 288;
      f1wT[t] = f2bf(f1[k*72 + n]);
    } else {
      int t = idx - (N1 + N2 + N3); int n = t / 96, k = t - n * 96;
      f2wT[t] = (k < 72) ? f2bf(f2[k*288 + n]) : (u16)0;
    }
    return;
  }
  // ------- patches + LN1 branch -------
  int b = bid >> 7, i = (bid >> 1) & 63, j0 = (bid & 1) * 32;
  int q = tid >> 5;
  int jl = tid & 31;
  int j = j0 + jl;
  const float* xb = x + ((long)b * 32) * 4096;
  float s = 0.f, ss = 0.f;
#pragma unroll
  for (int c4 = 0; c4 < 4; ++c4){
    int c = q * 4 + c4;
    const float* xc = xb + c * 4096;
#pragma unroll
    for (int di = 0; di < 3; ++di){
      int ii = i + di - 1;
      bool iok = (ii >= 0) && (ii < 64);
#pragma unroll
      for (int dj = 0; dj < 3; ++dj){
        int jj = j + dj - 1;
        float v = 0.f;
        if (iok && jj >= 0 && jj < 64) v = xc[ii * 64 + jj];
        lds_t[jl][c * 9 + di * 3 + dj] = v;
        s += v; ss += v * v;
      }
    }
  }
  red_s[q][jl] = s; red_q[q][jl] = ss;
  __syncthreads();
  if (q == 0){
    float S = 0.f, SS = 0.f;
#pragma unroll
    for (int k = 0; k < 8; ++k){ S += red_s[k][jl]; SS += red_q[k][jl]; }
    float mu = S * (1.f/288.f);
    float var = SS * (1.f/288.f) - mu * mu;
    smu[jl] = mu;
    srs[jl] = rsqrtf(var + 1e-5f);
  }
  __syncthreads();
  long rowbase = ((long)b * 4096 + i * 64 + j0) * 288;
  for (int it = 0; it < 9; ++it){
    int idx = tid + it * 256;
    int p = idx / 72;
    int kk = idx - p * 72;
    f32x4 v = *(f32x4*)&lds_t[p][kk * 4];
    long base = rowbase + (long)p * 288 + kk * 4;
    u32x2 pt;
    pt[0] = (u32)f2bf(v[0]) | ((u32)f2bf(v[1]) << 16);
    pt[1] = (u32)f2bf(v[2]) | ((u32)f2bf(v[3]) << 16);
    *(u32x2*)&tb[base] = pt;
    float mu = smu[p], rs = srs[p];
    u16 o0 = f2bf((v[0]-mu)*rs*g[kk*4+0] + b_[kk*4+0]);
    u16 o1 = f2bf((v[1]-mu)*rs*g[kk*4+1] + b_[kk*4+1]);
    u16 o2 = f2bf((v[2]-mu)*rs*g[kk*4+2] + b_[kk*4+2]);
    u16 o3 = f2bf((v[3]-mu)*rs*g[kk*4+3] + b_[kk*4+3]);
    u32x2 pk;
    pk[0] = (u32)o0 | ((u32)o1 << 16);
    pk[1] = (u32)o2 | ((u32)o3 << 16);
    *(u32x2*)&ln1[base] = pk;
  }
}

// ---------------- generic MFMA GEMM: C[M,N] = A[M,K](bf16) @ BT[N][KP](bf16) ----
// MODE 0: qkv scatter into Q/K [bch][1024][32] + V [bch][seg][32][256]; writes
//         Q-pads (d 18..31 = 0) and V ones-row (d=18 = 1.0) as part of epilogue.
// MODE 1: proj: +bias, +res(bf16), out bf16
template<int MODE, int KP, int MR>
__global__ __launch_bounds__(256) void gemm_k(
    const u16* __restrict__ A, const u16* __restrict__ BT,
    const float* __restrict__ bias, const void* __restrict__ resp,
    void* __restrict__ out0, void* __restrict__ out1, void* __restrict__ out2,
    int M, int N, int K)
{
  __shared__ u16 As[MR][KP + 8];
  __shared__ u16 Bs[64][KP + 8];
  const int nseg = KP >> 3;
  int tid = threadIdx.x;
  int m0 = blockIdx.x * MR, n0 = blockIdx.y * 64;
  for (int idx = tid; idx < (MR + 64) * nseg; idx += 256){
    int r = idx / nseg, sg = idx - r * nseg;
    if (r < MR){
      s16x8 v = {0,0,0,0,0,0,0,0};
      if (sg * 8 < K) v = *(const s16x8*)(A + (long)(m0 + r) * K + sg * 8);
      *(s16x8*)&As[r][sg * 8] = v;
    } else {
      int rb = r - MR;
      s16x8 w = {0,0,0,0,0,0,0,0};
      if (n0 + rb < N) w = *(const s16x8*)(BT + (long)(n0 + rb) * KP + sg * 8);
      *(s16x8*)&Bs[rb][sg * 8] = w;
    }
  }
  __syncthreads();
  int wv = tid >> 6, l = tid & 63;
  int lq = l & 15, lg = l >> 4;

#define EPI(ACC, MROW, NCOL) {                                           \
    int mrow = (MROW);                                                   \
    int ncol = (NCOL);                                                   \
    if (ncol < N){                                                       \
      if (MODE == 0){                                                    \
        int which = ncol / 144;                                          \
        int rem = ncol - which * 144;                                    \
        int hh = rem / 18;                                               \
        int dd = rem - hh * 18;                                          \
        _Pragma("unroll")                                                \
        for (int e = 0; e < 4; ++e){                                     \
          int row = mrow + e;                                            \
          long bch = (long)((row >> 10) * 8 + hh);                       \
          int kk = row & 1023;                                           \
          float v = ACC[e];                                              \
          if (which == 0){                                               \
            ((u16*)out0)[(bch<<15) + kk*32 + dd] = f2bf(v * QSCALE);     \
            if (dd < 14) ((u16*)out0)[(bch<<15) + kk*32 + 18 + dd] = (u16)0; \
          } else if (which == 1){                                        \
            int cp = (dd >> 3) ^ ((kk >> 1) & 3);                        \
            ((u16*)out1)[(bch<<15) + kk*32 + (cp<<3) + (dd&7)] = f2bf(v);\
          } else {                                                       \
            int seg = kk >> 8, jg = (kk >> 3) & 31, jp = jg ^ (dd & 7);  \
            ((u16*)out2)[(bch<<15) + seg*8192 + dd*256 + (jp<<3) + (kk&7)] = f2bf(v); \
            if (dd == 0){                                                \
              int jp1 = jg ^ 2;                                          \
              ((u16*)out2)[(bch<<15) + seg*8192 + 18*256 + (jp1<<3) + (kk&7)] = (u16)0x3F80; \
            }                                                            \
          }                                                              \
        }                                                                \
      } else {                                                           \
        float bv = bias[ncol];                                           \
        _Pragma("unroll")                                                \
        for (int e = 0; e < 4; ++e){                                     \
          long off = (long)(mrow + e) * N + ncol;                        \
          float v = ACC[e] + bv;                                         \
          if (MODE == 1){ v += bf2f(((const u16*)resp)[off]); ((u16*)out0)[off] = f2bf(v); } \
        }                                                                \
      }                                                                  \
    }                                                                    \
  }

  if constexpr (MR == 64){
    int wr = wv >> 1, wc = wv & 1;
    f32x4 acc00={0,0,0,0}, acc01={0,0,0,0}, acc10={0,0,0,0}, acc11={0,0,0,0};
    for (int kt = 0; kt < KP; kt += 32){
      s16x8 a0 = *(const s16x8*)&As[wr*32 + lq][kt + lg*8];
      s16x8 a1 = *(const s16x8*)&As[wr*32 + 16 + lq][kt + lg*8];
      s16x8 b0 = *(const s16x8*)&Bs[wc*32 + lq][kt + lg*8];
      s16x8 b1 = *(const s16x8*)&Bs[wc*32 + 16 + lq][kt + lg*8];
      acc00 = __builtin_amdgcn_mfma_f32_16x16x32_bf16(a0, b0, acc00, 0, 0, 0);
      acc01 = __builtin_amdgcn_mfma_f32_16x16x32_bf16(a0, b1, acc01, 0, 0, 0);
      acc10 = __builtin_amdgcn_mfma_f32_16x16x32_bf16(a1, b0, acc10, 0, 0, 0);
      acc11 = __builtin_amdgcn_mfma_f32_16x16x32_bf16(a1, b1, acc11, 0, 0, 0);
    }
    EPI(acc00, m0 + wr*32 + 0*16 + lg*4, n0 + wc*32 + 0*16 + lq)
    EPI(acc01, m0 + wr*32 + 0*16 + lg*4, n0 + wc*32 + 1*16 + lq)
    EPI(acc10, m0 + wr*32 + 1*16 + lg*4, n0 + wc*32 + 0*16 + lq)
    EPI(acc11, m0 + wr*32 + 1*16 + lg*4, n0 + wc*32 + 1*16 + lq)
  } else {
    f32x4 c00={0,0,0,0}, c01={0,0,0,0}, c02={0,0,0,0}, c03={0,0,0,0};
    f32x4 c10={0,0,0,0}, c11={0,0,0,0}, c12={0,0,0,0}, c13={0,0,0,0};
    for (int kt = 0; kt < KP; kt += 32){
      s16x8 a0 = *(const s16x8*)&As[wv*32 + lq][kt + lg*8];
      s16x8 a1 = *(const s16x8*)&As[wv*32 + 16 + lq][kt + lg*8];
      s16x8 b0 = *(const s16x8*)&Bs[ 0 + lq][kt + lg*8];
      s16x8 b1 = *(const s16x8*)&Bs[16 + lq][kt + lg*8];
      s16x8 b2 = *(const s16x8*)&Bs[32 + lq][kt + lg*8];
      s16x8 b3 = *(const s16x8*)&Bs[48 + lq][kt + lg*8];
      c00 = __builtin_amdgcn_mfma_f32_16x16x32_bf16(a0, b0, c00, 0, 0, 0);
      c01 = __builtin_amdgcn_mfma_f32_16x16x32_bf16(a0, b1, c01, 0, 0, 0);
      c02 = __builtin_amdgcn_mfma_f32_16x16x32_bf16(a0, b2, c02, 0, 0, 0);
      c03 = __builtin_amdgcn_mfma_f32_16x16x32_bf16(a0, b3, c03, 0, 0, 0);
      c10 = __builtin_amdgcn_mfma_f32_16x16x32_bf16(a1, b0, c10, 0, 0, 0);
      c11 = __builtin_amdgcn_mfma_f32_16x16x32_bf16(a1, b1, c11, 0, 0, 0);
      c12 = __builtin_amdgcn_mfma_f32_16x16x32_bf16(a1, b2, c12, 0, 0, 0);
      c13 = __builtin_amdgcn_mfma_f32_16x16x32_bf16(a1, b3, c13, 0, 0, 0);
    }
    EPI(c00, m0 + wv*32 + lg*4,      n0 +  0 + lq)
    EPI(c01, m0 + wv*32 + lg*4,      n0 + 16 + lq)
    EPI(c02, m0 + wv*32 + lg*4,      n0 + 32 + lq)
    EPI(c03, m0 + wv*32 + lg*4,      n0 + 48 + lq)
    EPI(c10, m0 + wv*32 + 16 + lg*4, n0 +  0 + lq)
    EPI(c11, m0 + wv*32 + 16 + lg*4, n0 + 16 + lq)
    EPI(c12, m0 + wv*32 + 16 + lg*4, n0 + 32 + lq)
    EPI(c13, m0 + wv*32 + 16 + lg*4, n0 + 48 + lq)
  }
#undef EPI
}

// ---------------- fused chunked attention (read-side sigma, 4 q-frags/wave) -----
// grid 512: bid = qt*128 + bch (bid%8 = h keeps one bch panel per XCD; qt 0..3).
// wave = 64 q-rows (4 q-frags) x 1024 k; K/V reg-prefetched per 256-k segment.
// V stored IDENTITY in k. PV B-operand slots 8lg+r need k = k0+4lg+r (r<4) /
// k0+16+4lg+(r-4) (r>=4) — the P values this lane owns from QK^T D-frags.
// pb = 4 cvtpk of own regs; va/vb via two 8B half-granule LDS reads.
// V row d=18 all-ones -> oB[j][2] = sum(exp) = L.
__global__ __launch_bounds__(256) void attn_k(
    const u16* __restrict__ Qp, const u16* __restrict__ Kpp,
    const u16* __restrict__ Vt, u16* __restrict__ ao)
{
  __shared__ u16 Ks[8192];
  __shared__ u16 Vs[8192];
  int bid = blockIdx.x;
  int qt = bid >> 7, bch = bid & 127;
  int b = bch >> 5, c = (bch >> 3) & 3, h = bch & 7;
  int tid = threadIdx.x, wv = tid >> 6, l = tid & 63;
  int lq = l & 15, lg = l >> 4;
  long base = (long)bch << 15;
  int q0 = qt * 256 + wv * 64 + lq;
  s16x8 qf0 = *(const s16x8*)(Qp + base + (long)(q0     ) * 32 + lg * 8);
  s16x8 qf1 = *(const s16x8*)(Qp + base + (long)(q0 + 16) * 32 + lg * 8);
  s16x8 qf2 = *(const s16x8*)(Qp + base + (long)(q0 + 32) * 32 + lg * 8);
  s16x8 qf3 = *(const s16x8*)(Qp + base + (long)(q0 + 48) * 32 + lg * 8);
  f32x4 oA0={0,0,0,0}, oA1={0,0,0,0}, oA2={0,0,0,0}, oA3={0,0,0,0};
  f32x4 oB0={0,0,0,0}, oB1={0,0,0,0}, oB2={0,0,0,0}, oB3={0,0,0,0};
  const f32x4 zf = {0,0,0,0};
  const u16* kg = Kpp + base;
  const u16* vg = Vt + base;
  u32x4 kr[4], vr[4];
#pragma unroll
  for (int r = 0; r < 4; ++r){
    kr[r] = *(const u32x4*)(kg + (r*256 + tid) * 8);
    vr[r] = *(const u32x4*)(vg + (r*256 + tid) * 8);
  }
  int kswz = (lq >> 1) & 3;
  int vswz = lq & 7;
  int ho = (lg & 1) << 2;         // half-granule offset (u16 units)
  int gl = lg >> 1;               // granule sub-index
  for (int seg = 0; seg < 4; ++seg){
    __syncthreads();
#pragma unroll
    for (int r = 0; r < 4; ++r){
      *(u32x4*)&Ks[(r*256 + tid) * 8] = kr[r];
      *(u32x4*)&Vs[(r*256 + tid) * 8] = vr[r];
    }
    __syncthreads();
    if (seg < 3){
      const u16* kgn = kg + (seg + 1) * 8192;
      const u16* vgn = vg + (seg + 1) * 8192;
#pragma unroll
      for (int r = 0; r < 4; ++r){
        kr[r] = *(const u32x4*)(kgn + (r*256 + tid) * 8);
        vr[r] = *(const u32x4*)(vgn + (r*256 + tid) * 8);
      }
    }
#pragma unroll 2
    for (int t32 = 0; t32 < 8; ++t32){
      int k0 = t32 * 32;
      int r0 = k0 + lq, r1 = k0 + 16 + lq;
      s16x8 kf0 = *(const s16x8*)&Ks[r0*32 + ((lg ^ kswz) << 3)];
      s16x8 kf1 = *(const s16x8*)&Ks[r1*32 + ((lg ^ kswz) << 3)];
      f32x4 s00 = __builtin_amdgcn_mfma_f32_16x16x32_bf16(kf0, qf0, zf, 0, 0, 0);
      f32x4 s01 = __builtin_amdgcn_mfma_f32_16x16x32_bf16(kf0, qf1, zf, 0, 0, 0);
      f32x4 s02 = __builtin_amdgcn_mfma_f32_16x16x32_bf16(kf0, qf2, zf, 0, 0, 0);
      f32x4 s03 = __builtin_amdgcn_mfma_f32_16x16x32_bf16(kf0, qf3, zf, 0, 0, 0);
      f32x4 s10 = __builtin_amdgcn_mfma_f32_16x16x32_bf16(kf1, qf0, zf, 0, 0, 0);
      f32x4 s11 = __builtin_amdgcn_mfma_f32_16x16x32_bf16(kf1, qf1, zf, 0, 0, 0);
      f32x4 s12 = __builtin_amdgcn_mfma_f32_16x16x32_bf16(kf1, qf2, zf, 0, 0, 0);
      f32x4 s13 = __builtin_amdgcn_mfma_f32_16x16x32_bf16(kf1, qf3, zf, 0, 0, 0);
      s16x8 pb0, pb1, pb2, pb3;
      {
        u32x4 w0, w1, w2, w3;
        w0[0] = cvtpk(fexp2(s00[0]), fexp2(s00[1]));
        w0[1] = cvtpk(fexp2(s00[2]), fexp2(s00[3]));
        w0[2] = cvtpk(fexp2(s10[0]), fexp2(s10[1]));
        w0[3] = cvtpk(fexp2(s10[2]), fexp2(s10[3]));
        w1[0] = cvtpk(fexp2(s01[0]), fexp2(s01[1]));
        w1[1] = cvtpk(fexp2(s01[2]), fexp2(s01[3]));
        w1[2] = cvtpk(fexp2(s11[0]), fexp2(s11[1]));
        w1[3] = cvtpk(fexp2(s11[2]), fexp2(s11[3]));
        w2[0] = cvtpk(fexp2(s02[0]), fexp2(s02[1]));
        w2[1] = cvtpk(fexp2(s02[2]), fexp2(s02[3]));
        w2[2] = cvtpk(fexp2(s12[0]), fexp2(s12[1]));
        w2[3] = cvtpk(fexp2(s12[2]), fexp2(s12[3]));
        w3[0] = cvtpk(fexp2(s03[0]), fexp2(s03[1]));
        w3[1] = cvtpk(fexp2(s03[2]), fexp2(s03[3]));
        w3[2] = cvtpk(fexp2(s13[0]), fexp2(s13[1]));
        w3[3] = cvtpk(fexp2(s13[2]), fexp2(s13[3]));
        pb0 = __builtin_bit_cast(s16x8, w0);
        pb1 = __builtin_bit_cast(s16x8, w1);
        pb2 = __builtin_bit_cast(s16x8, w2);
        pb3 = __builtin_bit_cast(s16x8, w3);
      }
      // sigma split-read: slots 8lg+{0..3} <- k0+4lg+{0..3}; +{4..7} <- k0+16+4lg+{0..3}
      int G1 = (k0 >> 3) + gl;
      int a_lo = lq*256 + ((G1 ^ vswz) << 3) + ho;
      int a_hi = lq*256 + (((G1 + 2) ^ vswz) << 3) + ho;
      u32x2 vl0 = *(const u32x2*)&Vs[a_lo];
      u32x2 vh0 = *(const u32x2*)&Vs[a_hi];
      u32x2 vl1 = *(const u32x2*)&Vs[a_lo + 4096];
      u32x2 vh1 = *(const u32x2*)&Vs[a_hi + 4096];
      u32x4 vc0; vc0[0] = vl0[0]; vc0[1] = vl0[1]; vc0[2] = vh0[0]; vc0[3] = vh0[1];
      u32x4 vc1; vc1[0] = vl1[0]; vc1[1] = vl1[1]; vc1[2] = vh1[0]; vc1[3] = vh1[1];
      s16x8 va = __builtin_bit_cast(s16x8, vc0);
      s16x8 vb = __builtin_bit_cast(s16x8, vc1);
      oA0 = __builtin_amdgcn_mfma_f32_16x16x32_bf16(va, pb0, oA0, 0, 0, 0);
      oA1 = __builtin_amdgcn_mfma_f32_16x16x32_bf16(va, pb1, oA1, 0, 0, 0);
      oA2 = __builtin_amdgcn_mfma_f32_16x16x32_bf16(va, pb2, oA2, 0, 0, 0);
      oA3 = __builtin_amdgcn_mfma_f32_16x16x32_bf16(va, pb3, oA3, 0, 0, 0);
      oB0 = __builtin_amdgcn_mfma_f32_16x16x32_bf16(vb, pb0, oB0, 0, 0, 0);
      oB1 = __builtin_amdgcn_mfma_f32_16x16x32_bf16(vb, pb1, oB1, 0, 0, 0);
      oB2 = __builtin_amdgcn_mfma_f32_16x16x32_bf16(vb, pb2, oB2, 0, 0, 0);
      oB3 = __builtin_amdgcn_mfma_f32_16x16x32_bf16(vb, pb3, oB3, 0, 0, 0);
    }
  }
  long cn = (long)b * 4096 + c * 1024;
#define OUTJ(J, OA, OB) {                                                \
    float L = __shfl(OB[2], lq, 64);                                     \
    float rL = 1.f / L;                                                  \
    long ob = (cn + q0 + 16*(J)) * 144 + h * 18;                         \
    _Pragma("unroll")                                                    \
    for (int e = 0; e < 4; ++e)                                          \
      ao[ob + lg * 4 + e] = f2bf(OA[e] * rL);                            \
    if (lg == 0){                                                        \
      ao[ob + 16] = f2bf(OB[0] * rL);                                    \
      ao[ob + 17] = f2bf(OB[1] * rL);                                    \
    }                                                                    \
  }
  OUTJ(0, oA0, oB0)
  OUTJ(1, oA1, oB1)
  OUTJ(2, oA2, oB2)
  OUTJ(3, oA3, oB3)
#undef OUTJ
}

// ---------------- fused LN2 + fc1(relu) + fc2 + residual ------------------------
// 4 waves per block, 64 rows; each wave owns 16 rows.
__global__ __launch_bounds__(256) void mlp_k(
    const u16* __restrict__ t2, const float* __restrict__ g, const float* __restrict__ b_,
    const u16* __restrict__ f1wT, const float* __restrict__ f1b,
    const u16* __restrict__ f2wT, const float* __restrict__ f2b,
    float* __restrict__ out)
{
  __shared__ u16 T2s[64][296];
  __shared__ u16 H1s[64][104];
  __shared__ float smu[64], srs[64];
  int tid = threadIdx.x;
  int wv = tid >> 6, l = tid & 63;
  int lq = l & 15, lg = l >> 4;
  long row0 = (long)blockIdx.x * 64;
  for (int idx = tid; idx < 64*36; idx += 256){
    int r = idx / 36, sg = idx - r*36;
    *(s16x8*)&T2s[r][sg*8] = *(const s16x8*)(t2 + (row0 + r)*288 + sg*8);
  }
  for (int idx = tid; idx < 64*16; idx += 256){
    int r = idx >> 4, c2 = idx & 15;
    *(u32*)&H1s[r][72 + c2*2] = 0u;
  }
  __syncthreads();
  {
    int r = tid >> 2, qt = tid & 3;
    const u16* pr = &T2s[r][qt*72];
    float s = 0.f, ss = 0.f;
#pragma unroll 4
    for (int i = 0; i < 36; ++i){
      u32 w = *(const u32*)(pr + i*2);
      float a = bfu32lo(w), c = bfu32hi(w);
      s += a + c; ss += a*a + c*c;
    }
    s  += __shfl_xor(s, 1, 64);  s  += __shfl_xor(s, 2, 64);
    ss += __shfl_xor(ss, 1, 64); ss += __shfl_xor(ss, 2, 64);
    if (qt == 0){
      float mu = s * (1.f/288.f);
      float var = ss * (1.f/288.f) - mu*mu;
      smu[r] = mu; srs[r] = rsqrtf(var + 1e-5f);
    }
  }
  __syncthreads();
  int myrow = wv*16 + lq;
  float mu = smu[myrow], rs = srs[myrow];
  f32x4 a0={0,0,0,0}, a1={0,0,0,0}, a2={0,0,0,0}, a3={0,0,0,0}, a4={0,0,0,0};
  int n4c = (lq < 8) ? (64 + lq) : 71;   // clamp; cols >=72 discarded
#pragma unroll
  for (int kt = 0; kt < 9; ++kt){
    s16x8 raw = *(const s16x8*)&T2s[myrow][kt*32 + lg*8];
    f32x4 g0 = *(const f32x4*)(g  + kt*32 + lg*8);
    f32x4 g1 = *(const f32x4*)(g  + kt*32 + lg*8 + 4);
    f32x4 b0 = *(const f32x4*)(b_ + kt*32 + lg*8);
    f32x4 b1 = *(const f32x4*)(b_ + kt*32 + lg*8 + 4);
    s16x8 af;
#pragma unroll
    for (int i = 0; i < 4; ++i){
      af[i]   = (short)f2bf((bf2f((u16)raw[i])   - mu)*rs*g0[i] + b0[i]);
      af[4+i] = (short)f2bf((bf2f((u16)raw[4+i]) - mu)*rs*g1[i] + b1[i]);
    }
    s16x8 w0 = *(const s16x8*)(f1wT + (lq     )*288 + kt*32 + lg*8);
    s16x8 w1 = *(const s16x8*)(f1wT + (16 + lq)*288 + kt*32 + lg*8);
    s16x8 w2 = *(const s16x8*)(f1wT + (32 + lq)*288 + kt*32 + lg*8);
    s16x8 w3 = *(const s16x8*)(f1wT + (48 + lq)*288 + kt*32 + lg*8);
    s16x8 w4 = *(const s16x8*)(f1wT + (n4c    )*288 + kt*32 + lg*8);
    a0 = __builtin_amdgcn_mfma_f32_16x16x32_bf16(af, w0, a0, 0, 0, 0);
    a1 = __builtin_amdgcn_mfma_f32_16x16x32_bf16(af, w1, a1, 0, 0, 0);
    a2 = __builtin_amdgcn_mfma_f32_16x16x32_bf16(af, w2, a2, 0, 0, 0);
    a3 = __builtin_amdgcn_mfma_f32_16x16x32_bf16(af, w3, a3, 0, 0, 0);
    a4 = __builtin_amdgcn_mfma_f32_16x16x32_bf16(af, w4, a4, 0, 0, 0);
  }
#define H1W(ACC, F) { int n = (F)*16 + lq; if (n < 72){ float bv = f1b[n];        \
    _Pragma("unroll") for (int e = 0; e < 4; ++e)                                 \
      H1s[wv*16 + lg*4 + e][n] = f2bf(fmaxf(ACC[e] + bv, 0.f)); } }
  H1W(a0,0) H1W(a1,1) H1W(a2,2) H1W(a3,3) H1W(a4,4)
#undef H1W
  __syncthreads();
  f32x4 c[18];
#pragma unroll
  for (int f = 0; f < 18; ++f) c[f] = (f32x4){0,0,0,0};
#pragma unroll
  for (int kt = 0; kt < 3; ++kt){
    s16x8 af = *(const s16x8*)&H1s[myrow][kt*32 + lg*8];
#pragma unroll
    for (int f = 0; f < 18; ++f){
      s16x8 wf = *(const s16x8*)(f2wT + (f*16 + lq)*96 + kt*32 + lg*8);
      c[f] = __builtin_amdgcn_mfma_f32_16x16x32_bf16(af, wf, c[f], 0, 0, 0);
    }
  }
#pragma unroll
  for (int f = 0; f < 18; ++f){
    int col = f*16 + lq;
    float bv = f2b[col];
#pragma unroll
    for (int e = 0; e < 4; ++e){
      int rl = wv*16 + lg*4 + e;
      out[(row0 + rl)*288 + col] = c[f][e] + bv + bf2f(T2s[rl][col]);
    }
  }
}

// ---------------- launch ---------------------------------------------------------
extern "C" void kernel_launch(void* const* d_in, const int* in_sizes, int n_in,
                              void* d_out, int out_size, void* d_ws, size_t ws_size,
                              hipStream_t stream)
{
  const float* x   = (const float*)d_in[0];
  const float* n1g = (const float*)d_in[1];
  const float* n1b = (const float*)d_in[2];
  const float* rw  = (const float*)d_in[3];
  const float* qw  = (const float*)d_in[4];
  const float* pw  = (const float*)d_in[5];
  const float* pb  = (const float*)d_in[6];
  const float* n2g = (const float*)d_in[7];
  const float* n2b = (const float*)d_in[8];
  const float* f1w = (const float*)d_in[9];
  const float* f1b = (const float*)d_in[10];
  const float* f2w = (const float*)d_in[11];
  const float* f2b = (const float*)d_in[12];
  char* ws = (char*)d_ws;
  u16*   tb   = (u16*)(ws + 0);            // 9437184  bf16 residual t
  u16*   ln1b = (u16*)(ws + 9437184);      // 9437184  (dead after qkv)
  u16*   Qp   = (u16*)(ws + 18874368);     // 8388608  [128 bch][1024][32]
  u16*   Kp   = (u16*)(ws + 27262976);     // 8388608  swizzled
  u16*   Vtp  = (u16*)(ws + 35651584);     // 8388608  [128 bch][4 seg][32 d][256] identity-k
  u16*   aob  = (u16*)(ws + 44040192);     // 4718592  (dead after proj)
  u16*   t2   = (u16*)(ws + 18874368);     // aliases Qp (dead after attn)
  u16*   WcT  = (u16*)(ws + 48758784);     // 432*288*2 = 248832
  u16*   pwT  = (u16*)(ws + 49007616);     // 288*160*2 = 92160
  u16*   f1wT = (u16*)(ws + 49099776);     // 72*288*2  = 41472
  u16*   f2wT = (u16*)(ws + 49141248);     // 288*96*2  = 55296
  float* out  = (float*)d_out;

  // blocks 0..511: patches+LN1 ; 512..1366: weight prep (independent work)
  head_k<<<1367, 256, 0, stream>>>(x, n1g, n1b, tb, ln1b,
                                   rw, qw, pw, f1w, f2w, WcT, pwT, f1wT, f2wT);
  // qkv = ln1 @ Wc -> scattered into Qp/Kp/Vtp (+ Q-pad zeros, V ones row)
  gemm_k<0,288,64><<<dim3(256,7), 256, 0, stream>>>(ln1b, WcT, nullptr, nullptr, Qp, Kp, Vtp, MTOT, 432, 288);
  attn_k<<<512, 256, 0, stream>>>(Qp, Kp, Vtp, aob);
  // t2 = t + attn @ proj_w + proj_b  (bf16)
  gemm_k<1,160,64><<<dim3(256,5), 256, 0, stream>>>(aob, pwT, pb, tb, t2, nullptr, nullptr, MTOT, 288, 144);
  // out = t2 + relu(LN(t2) @ f1w + f1b) @ f2w + f2b   (fused, 4 waves/block)
  mlp_k<<<256, 256, 0, stream>>>(t2, n2g, n2b, f1wT, f1b, f2wT, f2b, out);
}

// Round 13
// 113.492 us; speedup vs baseline: 1.1359x; 1.0791x over previous
//
#include <hip/hip_runtime.h>
#include <hip/hip_bf16.h>

typedef __attribute__((ext_vector_type(4))) float f32x4;
typedef __attribute__((ext_vector_type(8))) short s16x8;
typedef __attribute__((ext_vector_type(2))) unsigned int u32x2;
typedef __attribute__((ext_vector_type(4))) unsigned int u32x4;
typedef unsigned short u16;
typedef unsigned int u32;

#define MTOT 16384
// scale * log2(e): scores come out pre-multiplied for v_exp_f32 (2^x)
#define QSCALE 0.34004649151f

__device__ __forceinline__ u16 f2bf(float f){
  u32 u = __builtin_bit_cast(u32, f);
  u = (u + 0x7fffu + ((u >> 16) & 1u)) >> 16;
  return (u16)u;
}
__device__ __forceinline__ float bf2f(u16 u){
  u32 x = ((u32)u) << 16;
  return __builtin_bit_cast(float, x);
}
__device__ __forceinline__ float bfu32lo(u32 w){ return __builtin_bit_cast(float, (u32)(w << 16)); }
__device__ __forceinline__ float bfu32hi(u32 w){ return __builtin_bit_cast(float, (u32)(w & 0xffff0000u)); }
__device__ __forceinline__ u32 cvtpk(float lo, float hi){
  u32 r;
  asm("v_cvt_pk_bf16_f32 %0, %1, %2" : "=v"(r) : "v"(lo), "v"(hi));
  return r;
}
// raw 2^x (Q pre-scaled by log2e): single v_exp_f32, no libm wrapper
__device__ __forceinline__ float fexp2(float x){
  float r;
  asm("v_exp_f32 %0, %1" : "=v"(r) : "v"(x));
  return r;
}

// ---------------- merged head: patches+LN1 (blocks 0..511) | weight prep (512..1366)
__global__ __launch_bounds__(256) void head_k(
    const float* __restrict__ x, const float* __restrict__ g, const float* __restrict__ b_,
    u16* __restrict__ tb, u16* __restrict__ ln1,
    const float* __restrict__ rw, const float* __restrict__ qw,
    const float* __restrict__ pw, const float* __restrict__ f1, const float* __restrict__ f2,
    u16* __restrict__ WcT, u16* __restrict__ pwT, u16* __restrict__ f1wT, u16* __restrict__ f2wT)
{
  __shared__ float lds_t[32][296];
  __shared__ float red_s[8][32];
  __shared__ float red_q[8][32];
  __shared__ float smu[32], srs[32];
  int bid = blockIdx.x;
  int tid = threadIdx.x;
  if (bid >= 512){
    // ------- weight prep branch -------
    int idx = (bid - 512) * 256 + tid;
    const int N1 = 288*432, N2 = 288*160, N3 = 72*288;
    if (idx < N1){
      int i = idx / 432, j = idx - i * 432;   // i ~ wave-uniform: rw broadcast, qw coalesced
      float acc = 0.f;
      for (int k = 0; k < 144; ++k) acc += rw[i*144 + k] * qw[k*432 + j];
      WcT[j*288 + i] = f2bf(acc);
    } else if (idx < N1 + N2){
      int t = idx - N1; int n = t / 160, k = t - n * 160;
      pwT[t] = (k < 144) ? f2bf(pw[k*288 + n]) : (u16)0;
    } else if (idx < N1 + N2 + N3){
      int t = idx - (N1 + N2); int n = t / 288, k = t - n * 288;
      f1wT[t] = f2bf(f1[k*72 + n]);
    } else {
      int t = idx - (N1 + N2 + N3); int n = t / 96, k = t - n * 96;
      f2wT[t] = (k < 72) ? f2bf(f2[k*288 + n]) : (u16)0;
    }
    return;
  }
  // ------- patches + LN1 branch -------
  int b = bid >> 7, i = (bid >> 1) & 63, j0 = (bid & 1) * 32;
  int q = tid >> 5;
  int jl = tid & 31;
  int j = j0 + jl;
  const float* xb = x + ((long)b * 32) * 4096;
  float s = 0.f, ss = 0.f;
#pragma unroll
  for (int c4 = 0; c4 < 4; ++c4){
    int c = q * 4 + c4;
    const float* xc = xb + c * 4096;
#pragma unroll
    for (int di = 0; di < 3; ++di){
      int ii = i + di - 1;
      bool iok = (ii >= 0) && (ii < 64);
#pragma unroll
      for (int dj = 0; dj < 3; ++dj){
        int jj = j + dj - 1;
        float v = 0.f;
        if (iok && jj >= 0 && jj < 64) v = xc[ii * 64 + jj];
        lds_t[jl][c * 9 + di * 3 + dj] = v;
        s += v; ss += v * v;
      }
    }
  }
  red_s[q][jl] = s; red_q[q][jl] = ss;
  __syncthreads();
  if (q == 0){
    float S = 0.f, SS = 0.f;
#pragma unroll
    for (int k = 0; k < 8; ++k){ S += red_s[k][jl]; SS += red_q[k][jl]; }
    float mu = S * (1.f/288.f);
    float var = SS * (1.f/288.f) - mu * mu;
    smu[jl] = mu;
    srs[jl] = rsqrtf(var + 1e-5f);
  }
  __syncthreads();
  long rowbase = ((long)b * 4096 + i * 64 + j0) * 288;
  for (int it = 0; it < 9; ++it){
    int idx = tid + it * 256;
    int p = idx / 72;
    int kk = idx - p * 72;
    f32x4 v = *(f32x4*)&lds_t[p][kk * 4];
    long base = rowbase + (long)p * 288 + kk * 4;
    u32x2 pt;
    pt[0] = (u32)f2bf(v[0]) | ((u32)f2bf(v[1]) << 16);
    pt[1] = (u32)f2bf(v[2]) | ((u32)f2bf(v[3]) << 16);
    *(u32x2*)&tb[base] = pt;
    float mu = smu[p], rs = srs[p];
    u16 o0 = f2bf((v[0]-mu)*rs*g[kk*4+0] + b_[kk*4+0]);
    u16 o1 = f2bf((v[1]-mu)*rs*g[kk*4+1] + b_[kk*4+1]);
    u16 o2 = f2bf((v[2]-mu)*rs*g[kk*4+2] + b_[kk*4+2]);
    u16 o3 = f2bf((v[3]-mu)*rs*g[kk*4+3] + b_[kk*4+3]);
    u32x2 pk;
    pk[0] = (u32)o0 | ((u32)o1 << 16);
    pk[1] = (u32)o2 | ((u32)o3 << 16);
    *(u32x2*)&ln1[base] = pk;
  }
}

// ---------------- MFMA GEMM (MODE 0 only): qkv scatter --------------------------
// qkv scatter into Q/K [bch][1024][32] + V [bch][seg][32][256]; writes
// Q-pads (d 18..31 = 0) and V ones-row (d=18 = 1.0) as part of epilogue.
template<int MODE, int KP, int MR>
__global__ __launch_bounds__(256) void gemm_k(
    const u16* __restrict__ A, const u16* __restrict__ BT,
    const float* __restrict__ bias, const void* __restrict__ resp,
    void* __restrict__ out0, void* __restrict__ out1, void* __restrict__ out2,
    int M, int N, int K)
{
  __shared__ u16 As[MR][KP + 8];
  __shared__ u16 Bs[64][KP + 8];
  const int nseg = KP >> 3;
  int tid = threadIdx.x;
  int m0 = blockIdx.x * MR, n0 = blockIdx.y * 64;
  for (int idx = tid; idx < (MR + 64) * nseg; idx += 256){
    int r = idx / nseg, sg = idx - r * nseg;
    if (r < MR){
      s16x8 v = {0,0,0,0,0,0,0,0};
      if (sg * 8 < K) v = *(const s16x8*)(A + (long)(m0 + r) * K + sg * 8);
      *(s16x8*)&As[r][sg * 8] = v;
    } else {
      int rb = r - MR;
      s16x8 w = {0,0,0,0,0,0,0,0};
      if (n0 + rb < N) w = *(const s16x8*)(BT + (long)(n0 + rb) * KP + sg * 8);
      *(s16x8*)&Bs[rb][sg * 8] = w;
    }
  }
  __syncthreads();
  int wv = tid >> 6, l = tid & 63;
  int lq = l & 15, lg = l >> 4;

#define EPI(ACC, MROW, NCOL) {                                           \
    int mrow = (MROW);                                                   \
    int ncol = (NCOL);                                                   \
    if (ncol < N){                                                       \
      int which = ncol / 144;                                            \
      int rem = ncol - which * 144;                                      \
      int hh = rem / 18;                                                 \
      int dd = rem - hh * 18;                                            \
      _Pragma("unroll")                                                  \
      for (int e = 0; e < 4; ++e){                                       \
        int row = mrow + e;                                              \
        long bch = (long)((row >> 10) * 8 + hh);                         \
        int kk = row & 1023;                                             \
        float v = ACC[e];                                                \
        if (which == 0){                                                 \
          ((u16*)out0)[(bch<<15) + kk*32 + dd] = f2bf(v * QSCALE);       \
          if (dd < 14) ((u16*)out0)[(bch<<15) + kk*32 + 18 + dd] = (u16)0; \
        } else if (which == 1){                                          \
          int cp = (dd >> 3) ^ ((kk >> 1) & 3);                          \
          ((u16*)out1)[(bch<<15) + kk*32 + (cp<<3) + (dd&7)] = f2bf(v);  \
        } else {                                                         \
          int seg = kk >> 8, jg = (kk >> 3) & 31, jp = jg ^ (dd & 7);    \
          ((u16*)out2)[(bch<<15) + seg*8192 + dd*256 + (jp<<3) + (kk&7)] = f2bf(v); \
          if (dd == 0){                                                  \
            int jp1 = jg ^ 2;                                            \
            ((u16*)out2)[(bch<<15) + seg*8192 + 18*256 + (jp1<<3) + (kk&7)] = (u16)0x3F80; \
          }                                                              \
        }                                                                \
      }                                                                  \
    }                                                                    \
  }

  {
    int wr = wv >> 1, wc = wv & 1;
    f32x4 acc00={0,0,0,0}, acc01={0,0,0,0}, acc10={0,0,0,0}, acc11={0,0,0,0};
    for (int kt = 0; kt < KP; kt += 32){
      s16x8 a0 = *(const s16x8*)&As[wr*32 + lq][kt + lg*8];
      s16x8 a1 = *(const s16x8*)&As[wr*32 + 16 + lq][kt + lg*8];
      s16x8 b0 = *(const s16x8*)&Bs[wc*32 + lq][kt + lg*8];
      s16x8 b1 = *(const s16x8*)&Bs[wc*32 + 16 + lq][kt + lg*8];
      acc00 = __builtin_amdgcn_mfma_f32_16x16x32_bf16(a0, b0, acc00, 0, 0, 0);
      acc01 = __builtin_amdgcn_mfma_f32_16x16x32_bf16(a0, b1, acc01, 0, 0, 0);
      acc10 = __builtin_amdgcn_mfma_f32_16x16x32_bf16(a1, b0, acc10, 0, 0, 0);
      acc11 = __builtin_amdgcn_mfma_f32_16x16x32_bf16(a1, b1, acc11, 0, 0, 0);
    }
    EPI(acc00, m0 + wr*32 + 0*16 + lg*4, n0 + wc*32 + 0*16 + lq)
    EPI(acc01, m0 + wr*32 + 0*16 + lg*4, n0 + wc*32 + 1*16 + lq)
    EPI(acc10, m0 + wr*32 + 1*16 + lg*4, n0 + wc*32 + 0*16 + lq)
    EPI(acc11, m0 + wr*32 + 1*16 + lg*4, n0 + wc*32 + 1*16 + lq)
  }
#undef EPI
}

// ---------------- fused chunked attention (read-side sigma, 4 q-frags/wave) -----
// grid 512: bid = qt*128 + bch (bid%8 = h keeps one bch panel per XCD; qt 0..3).
// wave = 64 q-rows (4 q-frags) x 1024 k; K/V reg-prefetched per 256-k segment.
// V stored IDENTITY in k. PV B-operand slots 8lg+r need k = k0+4lg+r (r<4) /
// k0+16+4lg+(r-4) (r>=4) — the P values this lane owns from QK^T D-frags.
// pb = 4 cvtpk of own regs; va/vb via two 8B half-granule LDS reads.
// V row d=18 all-ones -> oB[j][2] = sum(exp) = L.
__global__ __launch_bounds__(256) void attn_k(
    const u16* __restrict__ Qp, const u16* __restrict__ Kpp,
    const u16* __restrict__ Vt, u16* __restrict__ ao)
{
  __shared__ u16 Ks[8192];
  __shared__ u16 Vs[8192];
  int bid = blockIdx.x;
  int qt = bid >> 7, bch = bid & 127;
  int b = bch >> 5, c = (bch >> 3) & 3, h = bch & 7;
  int tid = threadIdx.x, wv = tid >> 6, l = tid & 63;
  int lq = l & 15, lg = l >> 4;
  long base = (long)bch << 15;
  int q0 = qt * 256 + wv * 64 + lq;
  s16x8 qf0 = *(const s16x8*)(Qp + base + (long)(q0     ) * 32 + lg * 8);
  s16x8 qf1 = *(const s16x8*)(Qp + base + (long)(q0 + 16) * 32 + lg * 8);
  s16x8 qf2 = *(const s16x8*)(Qp + base + (long)(q0 + 32) * 32 + lg * 8);
  s16x8 qf3 = *(const s16x8*)(Qp + base + (long)(q0 + 48) * 32 + lg * 8);
  f32x4 oA0={0,0,0,0}, oA1={0,0,0,0}, oA2={0,0,0,0}, oA3={0,0,0,0};
  f32x4 oB0={0,0,0,0}, oB1={0,0,0,0}, oB2={0,0,0,0}, oB3={0,0,0,0};
  const f32x4 zf = {0,0,0,0};
  const u16* kg = Kpp + base;
  const u16* vg = Vt + base;
  u32x4 kr[4], vr[4];
#pragma unroll
  for (int r = 0; r < 4; ++r){
    kr[r] = *(const u32x4*)(kg + (r*256 + tid) * 8);
    vr[r] = *(const u32x4*)(vg + (r*256 + tid) * 8);
  }
  int kswz = (lq >> 1) & 3;
  int vswz = lq & 7;
  int ho = (lg & 1) << 2;         // half-granule offset (u16 units)
  int gl = lg >> 1;               // granule sub-index
  for (int seg = 0; seg < 4; ++seg){
    __syncthreads();
#pragma unroll
    for (int r = 0; r < 4; ++r){
      *(u32x4*)&Ks[(r*256 + tid) * 8] = kr[r];
      *(u32x4*)&Vs[(r*256 + tid) * 8] = vr[r];
    }
    __syncthreads();
    if (seg < 3){
      const u16* kgn = kg + (seg + 1) * 8192;
      const u16* vgn = vg + (seg + 1) * 8192;
#pragma unroll
      for (int r = 0; r < 4; ++r){
        kr[r] = *(const u32x4*)(kgn + (r*256 + tid) * 8);
        vr[r] = *(const u32x4*)(vgn + (r*256 + tid) * 8);
      }
    }
#pragma unroll 2
    for (int t32 = 0; t32 < 8; ++t32){
      int k0 = t32 * 32;
      int r0 = k0 + lq, r1 = k0 + 16 + lq;
      s16x8 kf0 = *(const s16x8*)&Ks[r0*32 + ((lg ^ kswz) << 3)];
      s16x8 kf1 = *(const s16x8*)&Ks[r1*32 + ((lg ^ kswz) << 3)];
      f32x4 s00 = __builtin_amdgcn_mfma_f32_16x16x32_bf16(kf0, qf0, zf, 0, 0, 0);
      f32x4 s01 = __builtin_amdgcn_mfma_f32_16x16x32_bf16(kf0, qf1, zf, 0, 0, 0);
      f32x4 s02 = __builtin_amdgcn_mfma_f32_16x16x32_bf16(kf0, qf2, zf, 0, 0, 0);
      f32x4 s03 = __builtin_amdgcn_mfma_f32_16x16x32_bf16(kf0, qf3, zf, 0, 0, 0);
      f32x4 s10 = __builtin_amdgcn_mfma_f32_16x16x32_bf16(kf1, qf0, zf, 0, 0, 0);
      f32x4 s11 = __builtin_amdgcn_mfma_f32_16x16x32_bf16(kf1, qf1, zf, 0, 0, 0);
      f32x4 s12 = __builtin_amdgcn_mfma_f32_16x16x32_bf16(kf1, qf2, zf, 0, 0, 0);
      f32x4 s13 = __builtin_amdgcn_mfma_f32_16x16x32_bf16(kf1, qf3, zf, 0, 0, 0);
      s16x8 pb0, pb1, pb2, pb3;
      {
        u32x4 w0, w1, w2, w3;
        w0[0] = cvtpk(fexp2(s00[0]), fexp2(s00[1]));
        w0[1] = cvtpk(fexp2(s00[2]), fexp2(s00[3]));
        w0[2] = cvtpk(fexp2(s10[0]), fexp2(s10[1]));
        w0[3] = cvtpk(fexp2(s10[2]), fexp2(s10[3]));
        w1[0] = cvtpk(fexp2(s01[0]), fexp2(s01[1]));
        w1[1] = cvtpk(fexp2(s01[2]), fexp2(s01[3]));
        w1[2] = cvtpk(fexp2(s11[0]), fexp2(s11[1]));
        w1[3] = cvtpk(fexp2(s11[2]), fexp2(s11[3]));
        w2[0] = cvtpk(fexp2(s02[0]), fexp2(s02[1]));
        w2[1] = cvtpk(fexp2(s02[2]), fexp2(s02[3]));
        w2[2] = cvtpk(fexp2(s12[0]), fexp2(s12[1]));
        w2[3] = cvtpk(fexp2(s12[2]), fexp2(s12[3]));
        w3[0] = cvtpk(fexp2(s03[0]), fexp2(s03[1]));
        w3[1] = cvtpk(fexp2(s03[2]), fexp2(s03[3]));
        w3[2] = cvtpk(fexp2(s13[0]), fexp2(s13[1]));
        w3[3] = cvtpk(fexp2(s13[2]), fexp2(s13[3]));
        pb0 = __builtin_bit_cast(s16x8, w0);
        pb1 = __builtin_bit_cast(s16x8, w1);
        pb2 = __builtin_bit_cast(s16x8, w2);
        pb3 = __builtin_bit_cast(s16x8, w3);
      }
      // sigma split-read: slots 8lg+{0..3} <- k0+4lg+{0..3}; +{4..7} <- k0+16+4lg+{0..3}
      int G1 = (k0 >> 3) + gl;
      int a_lo = lq*256 + ((G1 ^ vswz) << 3) + ho;
      int a_hi = lq*256 + (((G1 + 2) ^ vswz) << 3) + ho;
      u32x2 vl0 = *(const u32x2*)&Vs[a_lo];
      u32x2 vh0 = *(const u32x2*)&Vs[a_hi];
      u32x2 vl1 = *(const u32x2*)&Vs[a_lo + 4096];
      u32x2 vh1 = *(const u32x2*)&Vs[a_hi + 4096];
      u32x4 vc0; vc0[0] = vl0[0]; vc0[1] = vl0[1]; vc0[2] = vh0[0]; vc0[3] = vh0[1];
      u32x4 vc1; vc1[0] = vl1[0]; vc1[1] = vl1[1]; vc1[2] = vh1[0]; vc1[3] = vh1[1];
      s16x8 va = __builtin_bit_cast(s16x8, vc0);
      s16x8 vb = __builtin_bit_cast(s16x8, vc1);
      oA0 = __builtin_amdgcn_mfma_f32_16x16x32_bf16(va, pb0, oA0, 0, 0, 0);
      oA1 = __builtin_amdgcn_mfma_f32_16x16x32_bf16(va, pb1, oA1, 0, 0, 0);
      oA2 = __builtin_amdgcn_mfma_f32_16x16x32_bf16(va, pb2, oA2, 0, 0, 0);
      oA3 = __builtin_amdgcn_mfma_f32_16x16x32_bf16(va, pb3, oA3, 0, 0, 0);
      oB0 = __builtin_amdgcn_mfma_f32_16x16x32_bf16(vb, pb0, oB0, 0, 0, 0);
      oB1 = __builtin_amdgcn_mfma_f32_16x16x32_bf16(vb, pb1, oB1, 0, 0, 0);
      oB2 = __builtin_amdgcn_mfma_f32_16x16x32_bf16(vb, pb2, oB2, 0, 0, 0);
      oB3 = __builtin_amdgcn_mfma_f32_16x16x32_bf16(vb, pb3, oB3, 0, 0, 0);
    }
  }
  long cn = (long)b * 4096 + c * 1024;
#define OUTJ(J, OA, OB) {                                                \
    float L = __shfl(OB[2], lq, 64);                                     \
    float rL = 1.f / L;                                                  \
    long ob = (cn + q0 + 16*(J)) * 144 + h * 18;                         \
    _Pragma("unroll")                                                    \
    for (int e = 0; e < 4; ++e)                                          \
      ao[ob + lg * 4 + e] = f2bf(OA[e] * rL);                            \
    if (lg == 0){                                                        \
      ao[ob + 16] = f2bf(OB[0] * rL);                                    \
      ao[ob + 17] = f2bf(OB[1] * rL);                                    \
    }                                                                    \
  }
  OUTJ(0, oA0, oB0)
  OUTJ(1, oA1, oB1)
  OUTJ(2, oA2, oB2)
  OUTJ(3, oA3, oB3)
#undef OUTJ
}

// ---------------- fused tail: proj + residual + LN2 + fc1(relu) + fc2 + residual
// 4 waves per block, 64 rows; each wave owns 16 rows. t2 never touches HBM:
// proj accumulators + tb residual land in T2s (LDS bf16), then LN2/fc1/fc2 as
// the verified mlp_k structure.
__global__ __launch_bounds__(256) void tail_k(
    const u16* __restrict__ ao, const u16* __restrict__ pwT, const float* __restrict__ pbias,
    const u16* __restrict__ tbp,
    const float* __restrict__ g, const float* __restrict__ b_,
    const u16* __restrict__ f1wT, const float* __restrict__ f1b,
    const u16* __restrict__ f2wT, const float* __restrict__ f2b,
    float* __restrict__ out)
{
  __shared__ u16 AOs[64][168];    // proj A-tile, K padded 144->160 (+8 pad)
  __shared__ u16 T2s[64][296];
  __shared__ u16 H1s[64][104];
  __shared__ float smu[64], srs[64];
  int tid = threadIdx.x;
  int wv = tid >> 6, l = tid & 63;
  int lq = l & 15, lg = l >> 4;
  long row0 = (long)blockIdx.x * 64;
  // stage ao rows (zero-pad K cols 144..159)
  for (int idx = tid; idx < 64*20; idx += 256){
    int r = idx / 20, sg = idx - r*20;
    s16x8 v = {0,0,0,0,0,0,0,0};
    if (sg < 18) v = *(const s16x8*)(ao + (row0 + r)*144 + sg*8);
    *(s16x8*)&AOs[r][sg*8] = v;
  }
  // stage tb rows (residual; overwritten in-place with t2 after proj)
  for (int idx = tid; idx < 64*36; idx += 256){
    int r = idx / 36, sg = idx - r*36;
    *(s16x8*)&T2s[r][sg*8] = *(const s16x8*)(tbp + (row0 + r)*288 + sg*8);
  }
  for (int idx = tid; idx < 64*16; idx += 256){
    int r = idx >> 4, c2 = idx & 15;
    *(u32*)&H1s[r][72 + c2*2] = 0u;
  }
  __syncthreads();
  // ---- proj: t2 = tb + ao @ pw + pb  (18 col-frags x 5 k-steps, fc2 pattern) ----
  {
    f32x4 c[18];
#pragma unroll
    for (int f = 0; f < 18; ++f) c[f] = (f32x4){0,0,0,0};
#pragma unroll
    for (int kt = 0; kt < 5; ++kt){
      s16x8 af = *(const s16x8*)&AOs[wv*16 + lq][kt*32 + lg*8];
#pragma unroll
      for (int f = 0; f < 18; ++f){
        s16x8 wf = *(const s16x8*)(pwT + (long)(f*16 + lq)*160 + kt*32 + lg*8);
        c[f] = __builtin_amdgcn_mfma_f32_16x16x32_bf16(af, wf, c[f], 0, 0, 0);
      }
    }
#pragma unroll
    for (int f = 0; f < 18; ++f){
      int col = f*16 + lq;
      float bv = pbias[col];
#pragma unroll
      for (int e = 0; e < 4; ++e){
        int rl = wv*16 + lg*4 + e;     // each (rl,col) owned by exactly one lane
        float v = c[f][e] + bv + bf2f(T2s[rl][col]);
        T2s[rl][col] = f2bf(v);
      }
    }
  }
  __syncthreads();
  // ---- LN2 stats ----
  {
    int r = tid >> 2, qt = tid & 3;
    const u16* pr = &T2s[r][qt*72];
    float s = 0.f, ss = 0.f;
#pragma unroll 4
    for (int i = 0; i < 36; ++i){
      u32 w = *(const u32*)(pr + i*2);
      float a = bfu32lo(w), c = bfu32hi(w);
      s += a + c; ss += a*a + c*c;
    }
    s  += __shfl_xor(s, 1, 64);  s  += __shfl_xor(s, 2, 64);
    ss += __shfl_xor(ss, 1, 64); ss += __shfl_xor(ss, 2, 64);
    if (qt == 0){
      float mu = s * (1.f/288.f);
      float var = ss * (1.f/288.f) - mu*mu;
      smu[r] = mu; srs[r] = rsqrtf(var + 1e-5f);
    }
  }
  __syncthreads();
  int myrow = wv*16 + lq;
  float mu = smu[myrow], rs = srs[myrow];
  f32x4 a0={0,0,0,0}, a1={0,0,0,0}, a2={0,0,0,0}, a3={0,0,0,0}, a4={0,0,0,0};
  int n4c = (lq < 8) ? (64 + lq) : 71;   // clamp; cols >=72 discarded
#pragma unroll
  for (int kt = 0; kt < 9; ++kt){
    s16x8 raw = *(const s16x8*)&T2s[myrow][kt*32 + lg*8];
    f32x4 g0 = *(const f32x4*)(g  + kt*32 + lg*8);
    f32x4 g1 = *(const f32x4*)(g  + kt*32 + lg*8 + 4);
    f32x4 b0 = *(const f32x4*)(b_ + kt*32 + lg*8);
    f32x4 b1 = *(const f32x4*)(b_ + kt*32 + lg*8 + 4);
    s16x8 af;
#pragma unroll
    for (int i = 0; i < 4; ++i){
      af[i]   = (short)f2bf((bf2f((u16)raw[i])   - mu)*rs*g0[i] + b0[i]);
      af[4+i] = (short)f2bf((bf2f((u16)raw[4+i]) - mu)*rs*g1[i] + b1[i]);
    }
    s16x8 w0 = *(const s16x8*)(f1wT + (lq     )*288 + kt*32 + lg*8);
    s16x8 w1 = *(const s16x8*)(f1wT + (16 + lq)*288 + kt*32 + lg*8);
    s16x8 w2 = *(const s16x8*)(f1wT + (32 + lq)*288 + kt*32 + lg*8);
    s16x8 w3 = *(const s16x8*)(f1wT + (48 + lq)*288 + kt*32 + lg*8);
    s16x8 w4 = *(const s16x8*)(f1wT + (n4c    )*288 + kt*32 + lg*8);
    a0 = __builtin_amdgcn_mfma_f32_16x16x32_bf16(af, w0, a0, 0, 0, 0);
    a1 = __builtin_amdgcn_mfma_f32_16x16x32_bf16(af, w1, a1, 0, 0, 0);
    a2 = __builtin_amdgcn_mfma_f32_16x16x32_bf16(af, w2, a2, 0, 0, 0);
    a3 = __builtin_amdgcn_mfma_f32_16x16x32_bf16(af, w3, a3, 0, 0, 0);
    a4 = __builtin_amdgcn_mfma_f32_16x16x32_bf16(af, w4, a4, 0, 0, 0);
  }
#define H1W(ACC, F) { int n = (F)*16 + lq; if (n < 72){ float bv = f1b[n];        \
    _Pragma("unroll") for (int e = 0; e < 4; ++e)                                 \
      H1s[wv*16 + lg*4 + e][n] = f2bf(fmaxf(ACC[e] + bv, 0.f)); } }
  H1W(a0,0) H1W(a1,1) H1W(a2,2) H1W(a3,3) H1W(a4,4)
#undef H1W
  __syncthreads();
  f32x4 c[18];
#pragma unroll
  for (int f = 0; f < 18; ++f) c[f] = (f32x4){0,0,0,0};
#pragma unroll
  for (int kt = 0; kt < 3; ++kt){
    s16x8 af = *(const s16x8*)&H1s[myrow][kt*32 + lg*8];
#pragma unroll
    for (int f = 0; f < 18; ++f){
      s16x8 wf = *(const s16x8*)(f2wT + (f*16 + lq)*96 + kt*32 + lg*8);
      c[f] = __builtin_amdgcn_mfma_f32_16x16x32_bf16(af, wf, c[f], 0, 0, 0);
    }
  }
#pragma unroll
  for (int f = 0; f < 18; ++f){
    int col = f*16 + lq;
    float bv = f2b[col];
#pragma unroll
    for (int e = 0; e < 4; ++e){
      int rl = wv*16 + lg*4 + e;
      out[(row0 + rl)*288 + col] = c[f][e] + bv + bf2f(T2s[rl][col]);
    }
  }
}

// ---------------- launch ---------------------------------------------------------
extern "C" void kernel_launch(void* const* d_in, const int* in_sizes, int n_in,
                              void* d_out, int out_size, void* d_ws, size_t ws_size,
                              hipStream_t stream)
{
  const float* x   = (const float*)d_in[0];
  const float* n1g = (const float*)d_in[1];
  const float* n1b = (const float*)d_in[2];
  const float* rw  = (const float*)d_in[3];
  const float* qw  = (const float*)d_in[4];
  const float* pw  = (const float*)d_in[5];
  const float* pb  = (const float*)d_in[6];
  const float* n2g = (const float*)d_in[7];
  const float* n2b = (const float*)d_in[8];
  const float* f1w = (const float*)d_in[9];
  const float* f1b = (const float*)d_in[10];
  const float* f2w = (const float*)d_in[11];
  const float* f2b = (const float*)d_in[12];
  char* ws = (char*)d_ws;
  u16*   tb   = (u16*)(ws + 0);            // 9437184  bf16 residual t
  u16*   ln1b = (u16*)(ws + 9437184);      // 9437184  (dead after qkv)
  u16*   Qp   = (u16*)(ws + 18874368);     // 8388608  [128 bch][1024][32]
  u16*   Kp   = (u16*)(ws + 27262976);     // 8388608  swizzled
  u16*   Vtp  = (u16*)(ws + 35651584);     // 8388608  [128 bch][4 seg][32 d][256] identity-k
  u16*   aob  = (u16*)(ws + 44040192);     // 4718592
  u16*   WcT  = (u16*)(ws + 48758784);     // 432*288*2 = 248832
  u16*   pwT  = (u16*)(ws + 49007616);     // 288*160*2 = 92160
  u16*   f1wT = (u16*)(ws + 49099776);     // 72*288*2  = 41472
  u16*   f2wT = (u16*)(ws + 49141248);     // 288*96*2  = 55296
  float* out  = (float*)d_out;

  // blocks 0..511: patches+LN1 ; 512..1366: weight prep (independent work)
  head_k<<<1367, 256, 0, stream>>>(x, n1g, n1b, tb, ln1b,
                                   rw, qw, pw, f1w, f2w, WcT, pwT, f1wT, f2wT);
  // qkv = ln1 @ Wc -> scattered into Qp/Kp/Vtp (+ Q-pad zeros, V ones row)
  gemm_k<0,288,64><<<dim3(256,7), 256, 0, stream>>>(ln1b, WcT, nullptr, nullptr, Qp, Kp, Vtp, MTOT, 432, 288);
  attn_k<<<512, 256, 0, stream>>>(Qp, Kp, Vtp, aob);
  // out = t2 + relu(LN(t2) @ f1w + f1b) @ f2w + f2b, t2 = t + ao @ pw + pb (fused)
  tail_k<<<256, 256, 0, stream>>>(aob, pwT, pb, tb, n2g, n2b, f1wT, f1b, f2wT, f2b, out);
}

// Round 14
// 104.569 us; speedup vs baseline: 1.2328x; 1.0853x over previous
//
#include <hip/hip_runtime.h>
#include <hip/hip_bf16.h>

typedef __attribute__((ext_vector_type(4))) float f32x4;
typedef __attribute__((ext_vector_type(8))) short s16x8;
typedef __attribute__((ext_vector_type(2))) unsigned int u32x2;
typedef __attribute__((ext_vector_type(4))) unsigned int u32x4;
typedef unsigned short u16;
typedef unsigned int u32;

#define MTOT 16384
// scale * log2(e): scores come out pre-multiplied for v_exp_f32 (2^x)
#define QSCALE 0.34004649151f

__device__ __forceinline__ u16 f2bf(float f){
  u32 u = __builtin_bit_cast(u32, f);
  u = (u + 0x7fffu + ((u >> 16) & 1u)) >> 16;
  return (u16)u;
}
__device__ __forceinline__ float bf2f(u16 u){
  u32 x = ((u32)u) << 16;
  return __builtin_bit_cast(float, x);
}
__device__ __forceinline__ float bfu32lo(u32 w){ return __builtin_bit_cast(float, (u32)(w << 16)); }
__device__ __forceinline__ float bfu32hi(u32 w){ return __builtin_bit_cast(float, (u32)(w & 0xffff0000u)); }
__device__ __forceinline__ u32 cvtpk(float lo, float hi){
  u32 r;
  asm("v_cvt_pk_bf16_f32 %0, %1, %2" : "=v"(r) : "v"(lo), "v"(hi));
  return r;
}
// raw 2^x (Q pre-scaled by log2e): single v_exp_f32, no libm wrapper
__device__ __forceinline__ float fexp2(float x){
  float r;
  asm("v_exp_f32 %0, %1" : "=v"(r) : "v"(x));
  return r;
}

// ---------------- weight prep: transposed bf16 weights --------------------------
// WcT[432][288] = (reduce_w @ qkv_w)^T ; pwT[288][160]; f1wT[72][288]; f2wT[288][96]
__global__ __launch_bounds__(256) void prep_w_k(
    const float* __restrict__ rw, const float* __restrict__ qw,
    const float* __restrict__ pw, const float* __restrict__ f1, const float* __restrict__ f2,
    u16* __restrict__ WcT, u16* __restrict__ pwT, u16* __restrict__ f1wT, u16* __restrict__ f2wT)
{
  int idx = blockIdx.x * 256 + threadIdx.x;
  const int N1 = 288*432, N2 = 288*160, N3 = 72*288, N4 = 288*96;
  if (idx < N1){
    int i = idx / 432, j = idx - i * 432;     // i ~ wave-uniform: rw broadcast, qw coalesced
    float acc = 0.f;
    for (int k = 0; k < 144; ++k) acc += rw[i*144 + k] * qw[k*432 + j];
    WcT[j*288 + i] = f2bf(acc);
  } else if (idx < N1 + N2){
    int t = idx - N1; int n = t / 160, k = t - n * 160;
    pwT[t] = (k < 144) ? f2bf(pw[k*288 + n]) : (u16)0;
  } else if (idx < N1 + N2 + N3){
    int t = idx - (N1 + N2); int n = t / 288, k = t - n * 288;
    f1wT[t] = f2bf(f1[k*72 + n]);
  } else if (idx < N1 + N2 + N3 + N4){
    int t = idx - (N1 + N2 + N3); int n = t / 96, k = t - n * 96;
    f2wT[t] = (k < 72) ? f2bf(f2[k*288 + n]) : (u16)0;
  }
}

// ---------------- fused patches + LN1 + qkv GEMM + scatter ----------------------
// grid 512, block = 32 pixels. Patch tile stored bf16 in LDS (stats in f32);
// qkv = LN1(patch) @ WcT with LN applied on-the-fly to A-frags (tail_k pattern),
// WcT B-frags streamed from L2. Epilogue = verified MODE-0 scatter into
// Qp (scaled, pads zeroed) / Kp (swizzled) / Vtp (+ ones row d=18).
__global__ __launch_bounds__(256) void hq_k(
    const float* __restrict__ x, const float* __restrict__ g, const float* __restrict__ b_,
    u16* __restrict__ tb, const u16* __restrict__ WcT,
    u16* __restrict__ Qp, u16* __restrict__ Kp, u16* __restrict__ Vtp)
{
  __shared__ u16 Ts[32][296];
  __shared__ float red_s[8][32];
  __shared__ float red_q[8][32];
  __shared__ float smu[32], srs[32];
  int bid = blockIdx.x;
  int b = bid >> 7, i = (bid >> 1) & 63, j0 = (bid & 1) * 32;
  int tid = threadIdx.x;
  int q = tid >> 5;
  int jl = tid & 31;
  int j = j0 + jl;
  const float* xb = x + ((long)b * 32) * 4096;
  float s = 0.f, ss = 0.f;
#pragma unroll
  for (int c4 = 0; c4 < 4; ++c4){
    int c = q * 4 + c4;
    const float* xc = xb + c * 4096;
#pragma unroll
    for (int di = 0; di < 3; ++di){
      int ii = i + di - 1;
      bool iok = (ii >= 0) && (ii < 64);
#pragma unroll
      for (int dj = 0; dj < 3; ++dj){
        int jj = j + dj - 1;
        float v = 0.f;
        if (iok && jj >= 0 && jj < 64) v = xc[ii * 64 + jj];
        Ts[jl][c * 9 + di * 3 + dj] = f2bf(v);
        s += v; ss += v * v;
      }
    }
  }
  red_s[q][jl] = s; red_q[q][jl] = ss;
  __syncthreads();
  if (q == 0){
    float S = 0.f, SS = 0.f;
#pragma unroll
    for (int k = 0; k < 8; ++k){ S += red_s[k][jl]; SS += red_q[k][jl]; }
    float mu = S * (1.f/288.f);
    float var = SS * (1.f/288.f) - mu * mu;
    smu[jl] = mu;
    srs[jl] = rsqrtf(var + 1e-5f);
  }
  __syncthreads();
  // tb write (bf16 residual t)
  long rowbase = ((long)b * 4096 + i * 64 + j0) * 288;
  for (int idx = tid; idx < 32*36; idx += 256){
    int r = idx / 36, sg = idx - r * 36;
    *(u32x4*)(tb + rowbase + (long)r * 288 + sg * 8) = *(const u32x4*)&Ts[r][sg * 8];
  }
  // ---- qkv GEMM: rows = 32 pixels, cols = 432; wave wv owns col-frags f = wv+4t
  int wv = tid >> 6, l = tid & 63;
  int lq = l & 15, lg = l >> 4;
  int brow0 = bid * 32;
  float mu0 = smu[lq],      rs0 = srs[lq];
  float mu1 = smu[16 + lq], rs1 = srs[16 + lq];
  f32x4 c0[7], c1[7];
#pragma unroll
  for (int t = 0; t < 7; ++t){ c0[t] = (f32x4){0,0,0,0}; c1[t] = (f32x4){0,0,0,0}; }
#pragma unroll
  for (int kt = 0; kt < 9; ++kt){
    int ko = kt * 32 + lg * 8;
    f32x4 g0  = *(const f32x4*)(g  + ko);
    f32x4 g1  = *(const f32x4*)(g  + ko + 4);
    f32x4 bb0 = *(const f32x4*)(b_ + ko);
    f32x4 bb1 = *(const f32x4*)(b_ + ko + 4);
    s16x8 raw0 = *(const s16x8*)&Ts[lq][ko];
    s16x8 raw1 = *(const s16x8*)&Ts[16 + lq][ko];
    s16x8 af0, af1;
#pragma unroll
    for (int e = 0; e < 4; ++e){
      af0[e]   = (short)f2bf((bf2f((u16)raw0[e])   - mu0)*rs0*g0[e] + bb0[e]);
      af0[4+e] = (short)f2bf((bf2f((u16)raw0[4+e]) - mu0)*rs0*g1[e] + bb1[e]);
      af1[e]   = (short)f2bf((bf2f((u16)raw1[e])   - mu1)*rs1*g0[e] + bb0[e]);
      af1[4+e] = (short)f2bf((bf2f((u16)raw1[4+e]) - mu1)*rs1*g1[e] + bb1[e]);
    }
#pragma unroll
    for (int t = 0; t < 7; ++t){
      int f = wv + 4*t;
      if (f < 27){
        s16x8 wf = *(const s16x8*)(WcT + (long)(f*16 + lq)*288 + ko);
        c0[t] = __builtin_amdgcn_mfma_f32_16x16x32_bf16(af0, wf, c0[t], 0, 0, 0);
        c1[t] = __builtin_amdgcn_mfma_f32_16x16x32_bf16(af1, wf, c1[t], 0, 0, 0);
      }
    }
  }
  // ---- verified MODE-0 scatter epilogue ----
#define EPI(ACC, MROW, NCOL) {                                           \
    int mrow = (MROW);                                                   \
    int ncol = (NCOL);                                                   \
    {                                                                    \
      int which = ncol / 144;                                            \
      int rem = ncol - which * 144;                                      \
      int hh = rem / 18;                                                 \
      int dd = rem - hh * 18;                                            \
      _Pragma("unroll")                                                  \
      for (int e = 0; e < 4; ++e){                                       \
        int row = mrow + e;                                              \
        long bch = (long)((row >> 10) * 8 + hh);                         \
        int kk = row & 1023;                                             \
        float v = ACC[e];                                                \
        if (which == 0){                                                 \
          Qp[(bch<<15) + kk*32 + dd] = f2bf(v * QSCALE);                 \
          if (dd < 14) Qp[(bch<<15) + kk*32 + 18 + dd] = (u16)0;         \
        } else if (which == 1){                                          \
          int cp = (dd >> 3) ^ ((kk >> 1) & 3);                          \
          Kp[(bch<<15) + kk*32 + (cp<<3) + (dd&7)] = f2bf(v);            \
        } else {                                                         \
          int seg = kk >> 8, jg = (kk >> 3) & 31, jp = jg ^ (dd & 7);    \
          Vtp[(bch<<15) + seg*8192 + dd*256 + (jp<<3) + (kk&7)] = f2bf(v); \
          if (dd == 0){                                                  \
            int jp1 = jg ^ 2;                                            \
            Vtp[(bch<<15) + seg*8192 + 18*256 + (jp1<<3) + (kk&7)] = (u16)0x3F80; \
          }                                                              \
        }                                                                \
      }                                                                  \
    }                                                                    \
  }
#pragma unroll
  for (int t = 0; t < 7; ++t){
    int f = wv + 4*t;
    if (f < 27){
      EPI(c0[t], brow0 + lg*4,      f*16 + lq)
      EPI(c1[t], brow0 + 16 + lg*4, f*16 + lq)
    }
  }
#undef EPI
}

// ---------------- fused chunked attention (read-side sigma, 4 q-frags/wave) -----
// grid 512: bid = qt*128 + bch (bid%8 = h keeps one bch panel per XCD; qt 0..3).
// wave = 64 q-rows (4 q-frags) x 1024 k; K/V reg-prefetched per 256-k segment.
// V stored IDENTITY in k. PV B-operand slots 8lg+r need k = k0+4lg+r (r<4) /
// k0+16+4lg+(r-4) (r>=4) — the P values this lane owns from QK^T D-frags.
// pb = 4 cvtpk of own regs; va/vb via two 8B half-granule LDS reads.
// V row d=18 all-ones -> oB[j][2] = sum(exp) = L.
__global__ __launch_bounds__(256) void attn_k(
    const u16* __restrict__ Qp, const u16* __restrict__ Kpp,
    const u16* __restrict__ Vt, u16* __restrict__ ao)
{
  __shared__ u16 Ks[8192];
  __shared__ u16 Vs[8192];
  int bid = blockIdx.x;
  int qt = bid >> 7, bch = bid & 127;
  int b = bch >> 5, c = (bch >> 3) & 3, h = bch & 7;
  int tid = threadIdx.x, wv = tid >> 6, l = tid & 63;
  int lq = l & 15, lg = l >> 4;
  long base = (long)bch << 15;
  int q0 = qt * 256 + wv * 64 + lq;
  s16x8 qf0 = *(const s16x8*)(Qp + base + (long)(q0     ) * 32 + lg * 8);
  s16x8 qf1 = *(const s16x8*)(Qp + base + (long)(q0 + 16) * 32 + lg * 8);
  s16x8 qf2 = *(const s16x8*)(Qp + base + (long)(q0 + 32) * 32 + lg * 8);
  s16x8 qf3 = *(const s16x8*)(Qp + base + (long)(q0 + 48) * 32 + lg * 8);
  f32x4 oA0={0,0,0,0}, oA1={0,0,0,0}, oA2={0,0,0,0}, oA3={0,0,0,0};
  f32x4 oB0={0,0,0,0}, oB1={0,0,0,0}, oB2={0,0,0,0}, oB3={0,0,0,0};
  const f32x4 zf = {0,0,0,0};
  const u16* kg = Kpp + base;
  const u16* vg = Vt + base;
  u32x4 kr[4], vr[4];
#pragma unroll
  for (int r = 0; r < 4; ++r){
    kr[r] = *(const u32x4*)(kg + (r*256 + tid) * 8);
    vr[r] = *(const u32x4*)(vg + (r*256 + tid) * 8);
  }
  int kswz = (lq >> 1) & 3;
  int vswz = lq & 7;
  int ho = (lg & 1) << 2;         // half-granule offset (u16 units)
  int gl = lg >> 1;               // granule sub-index
  for (int seg = 0; seg < 4; ++seg){
    __syncthreads();
#pragma unroll
    for (int r = 0; r < 4; ++r){
      *(u32x4*)&Ks[(r*256 + tid) * 8] = kr[r];
      *(u32x4*)&Vs[(r*256 + tid) * 8] = vr[r];
    }
    __syncthreads();
    if (seg < 3){
      const u16* kgn = kg + (seg + 1) * 8192;
      const u16* vgn = vg + (seg + 1) * 8192;
#pragma unroll
      for (int r = 0; r < 4; ++r){
        kr[r] = *(const u32x4*)(kgn + (r*256 + tid) * 8);
        vr[r] = *(const u32x4*)(vgn + (r*256 + tid) * 8);
      }
    }
#pragma unroll 2
    for (int t32 = 0; t32 < 8; ++t32){
      int k0 = t32 * 32;
      int r0 = k0 + lq, r1 = k0 + 16 + lq;
      s16x8 kf0 = *(const s16x8*)&Ks[r0*32 + ((lg ^ kswz) << 3)];
      s16x8 kf1 = *(const s16x8*)&Ks[r1*32 + ((lg ^ kswz) << 3)];
      f32x4 s00 = __builtin_amdgcn_mfma_f32_16x16x32_bf16(kf0, qf0, zf, 0, 0, 0);
      f32x4 s01 = __builtin_amdgcn_mfma_f32_16x16x32_bf16(kf0, qf1, zf, 0, 0, 0);
      f32x4 s02 = __builtin_amdgcn_mfma_f32_16x16x32_bf16(kf0, qf2, zf, 0, 0, 0);
      f32x4 s03 = __builtin_amdgcn_mfma_f32_16x16x32_bf16(kf0, qf3, zf, 0, 0, 0);
      f32x4 s10 = __builtin_amdgcn_mfma_f32_16x16x32_bf16(kf1, qf0, zf, 0, 0, 0);
      f32x4 s11 = __builtin_amdgcn_mfma_f32_16x16x32_bf16(kf1, qf1, zf, 0, 0, 0);
      f32x4 s12 = __builtin_amdgcn_mfma_f32_16x16x32_bf16(kf1, qf2, zf, 0, 0, 0);
      f32x4 s13 = __builtin_amdgcn_mfma_f32_16x16x32_bf16(kf1, qf3, zf, 0, 0, 0);
      s16x8 pb0, pb1, pb2, pb3;
      {
        u32x4 w0, w1, w2, w3;
        w0[0] = cvtpk(fexp2(s00[0]), fexp2(s00[1]));
        w0[1] = cvtpk(fexp2(s00[2]), fexp2(s00[3]));
        w0[2] = cvtpk(fexp2(s10[0]), fexp2(s10[1]));
        w0[3] = cvtpk(fexp2(s10[2]), fexp2(s10[3]));
        w1[0] = cvtpk(fexp2(s01[0]), fexp2(s01[1]));
        w1[1] = cvtpk(fexp2(s01[2]), fexp2(s01[3]));
        w1[2] = cvtpk(fexp2(s11[0]), fexp2(s11[1]));
        w1[3] = cvtpk(fexp2(s11[2]), fexp2(s11[3]));
        w2[0] = cvtpk(fexp2(s02[0]), fexp2(s02[1]));
        w2[1] = cvtpk(fexp2(s02[2]), fexp2(s02[3]));
        w2[2] = cvtpk(fexp2(s12[0]), fexp2(s12[1]));
        w2[3] = cvtpk(fexp2(s12[2]), fexp2(s12[3]));
        w3[0] = cvtpk(fexp2(s03[0]), fexp2(s03[1]));
        w3[1] = cvtpk(fexp2(s03[2]), fexp2(s03[3]));
        w3[2] = cvtpk(fexp2(s13[0]), fexp2(s13[1]));
        w3[3] = cvtpk(fexp2(s13[2]), fexp2(s13[3]));
        pb0 = __builtin_bit_cast(s16x8, w0);
        pb1 = __builtin_bit_cast(s16x8, w1);
        pb2 = __builtin_bit_cast(s16x8, w2);
        pb3 = __builtin_bit_cast(s16x8, w3);
      }
      // sigma split-read: slots 8lg+{0..3} <- k0+4lg+{0..3}; +{4..7} <- k0+16+4lg+{0..3}
      int G1 = (k0 >> 3) + gl;
      int a_lo = lq*256 + ((G1 ^ vswz) << 3) + ho;
      int a_hi = lq*256 + (((G1 + 2) ^ vswz) << 3) + ho;
      u32x2 vl0 = *(const u32x2*)&Vs[a_lo];
      u32x2 vh0 = *(const u32x2*)&Vs[a_hi];
      u32x2 vl1 = *(const u32x2*)&Vs[a_lo + 4096];
      u32x2 vh1 = *(const u32x2*)&Vs[a_hi + 4096];
      u32x4 vc0; vc0[0] = vl0[0]; vc0[1] = vl0[1]; vc0[2] = vh0[0]; vc0[3] = vh0[1];
      u32x4 vc1; vc1[0] = vl1[0]; vc1[1] = vl1[1]; vc1[2] = vh1[0]; vc1[3] = vh1[1];
      s16x8 va = __builtin_bit_cast(s16x8, vc0);
      s16x8 vb = __builtin_bit_cast(s16x8, vc1);
      oA0 = __builtin_amdgcn_mfma_f32_16x16x32_bf16(va, pb0, oA0, 0, 0, 0);
      oA1 = __builtin_amdgcn_mfma_f32_16x16x32_bf16(va, pb1, oA1, 0, 0, 0);
      oA2 = __builtin_amdgcn_mfma_f32_16x16x32_bf16(va, pb2, oA2, 0, 0, 0);
      oA3 = __builtin_amdgcn_mfma_f32_16x16x32_bf16(va, pb3, oA3, 0, 0, 0);
      oB0 = __builtin_amdgcn_mfma_f32_16x16x32_bf16(vb, pb0, oB0, 0, 0, 0);
      oB1 = __builtin_amdgcn_mfma_f32_16x16x32_bf16(vb, pb1, oB1, 0, 0, 0);
      oB2 = __builtin_amdgcn_mfma_f32_16x16x32_bf16(vb, pb2, oB2, 0, 0, 0);
      oB3 = __builtin_amdgcn_mfma_f32_16x16x32_bf16(vb, pb3, oB3, 0, 0, 0);
    }
  }
  long cn = (long)b * 4096 + c * 1024;
#define OUTJ(J, OA, OB) {                                                \
    float L = __shfl(OB[2], lq, 64);                                     \
    float rL = 1.f / L;                                                  \
    long ob = (cn + q0 + 16*(J)) * 144 + h * 18;                         \
    _Pragma("unroll")                                                    \
    for (int e = 0; e < 4; ++e)                                          \
      ao[ob + lg * 4 + e] = f2bf(OA[e] * rL);                            \
    if (lg == 0){                                                        \
      ao[ob + 16] = f2bf(OB[0] * rL);                                    \
      ao[ob + 17] = f2bf(OB[1] * rL);                                    \
    }                                                                    \
  }
  OUTJ(0, oA0, oB0)
  OUTJ(1, oA1, oB1)
  OUTJ(2, oA2, oB2)
  OUTJ(3, oA3, oB3)
#undef OUTJ
}

// ---------------- fused tail: proj + residual + LN2 + fc1(relu) + fc2 + residual
// 4 waves per block, 64 rows; each wave owns 16 rows. t2 never touches HBM.
__global__ __launch_bounds__(256) void tail_k(
    const u16* __restrict__ ao, const u16* __restrict__ pwT, const float* __restrict__ pbias,
    const u16* __restrict__ tbp,
    const float* __restrict__ g, const float* __restrict__ b_,
    const u16* __restrict__ f1wT, const float* __restrict__ f1b,
    const u16* __restrict__ f2wT, const float* __restrict__ f2b,
    float* __restrict__ out)
{
  __shared__ u16 AOs[64][168];    // proj A-tile, K padded 144->160 (+8 pad)
  __shared__ u16 T2s[64][296];
  __shared__ u16 H1s[64][104];
  __shared__ float smu[64], srs[64];
  int tid = threadIdx.x;
  int wv = tid >> 6, l = tid & 63;
  int lq = l & 15, lg = l >> 4;
  long row0 = (long)blockIdx.x * 64;
  // stage ao rows (zero-pad K cols 144..159)
  for (int idx = tid; idx < 64*20; idx += 256){
    int r = idx / 20, sg = idx - r*20;
    s16x8 v = {0,0,0,0,0,0,0,0};
    if (sg < 18) v = *(const s16x8*)(ao + (row0 + r)*144 + sg*8);
    *(s16x8*)&AOs[r][sg*8] = v;
  }
  // stage tb rows (residual; overwritten in-place with t2 after proj)
  for (int idx = tid; idx < 64*36; idx += 256){
    int r = idx / 36, sg = idx - r*36;
    *(s16x8*)&T2s[r][sg*8] = *(const s16x8*)(tbp + (row0 + r)*288 + sg*8);
  }
  for (int idx = tid; idx < 64*16; idx += 256){
    int r = idx >> 4, c2 = idx & 15;
    *(u32*)&H1s[r][72 + c2*2] = 0u;
  }
  __syncthreads();
  // ---- proj: t2 = tb + ao @ pw + pb  (18 col-frags x 5 k-steps) ----
  {
    f32x4 c[18];
#pragma unroll
    for (int f = 0; f < 18; ++f) c[f] = (f32x4){0,0,0,0};
#pragma unroll
    for (int kt = 0; kt < 5; ++kt){
      s16x8 af = *(const s16x8*)&AOs[wv*16 + lq][kt*32 + lg*8];
#pragma unroll
      for (int f = 0; f < 18; ++f){
        s16x8 wf = *(const s16x8*)(pwT + (long)(f*16 + lq)*160 + kt*32 + lg*8);
        c[f] = __builtin_amdgcn_mfma_f32_16x16x32_bf16(af, wf, c[f], 0, 0, 0);
      }
    }
#pragma unroll
    for (int f = 0; f < 18; ++f){
      int col = f*16 + lq;
      float bv = pbias[col];
#pragma unroll
      for (int e = 0; e < 4; ++e){
        int rl = wv*16 + lg*4 + e;     // each (rl,col) owned by exactly one lane
        float v = c[f][e] + bv + bf2f(T2s[rl][col]);
        T2s[rl][col] = f2bf(v);
      }
    }
  }
  __syncthreads();
  // ---- LN2 stats ----
  {
    int r = tid >> 2, qt = tid & 3;
    const u16* pr = &T2s[r][qt*72];
    float s = 0.f, ss = 0.f;
#pragma unroll 4
    for (int i = 0; i < 36; ++i){
      u32 w = *(const u32*)(pr + i*2);
      float a = bfu32lo(w), c = bfu32hi(w);
      s += a + c; ss += a*a + c*c;
    }
    s  += __shfl_xor(s, 1, 64);  s  += __shfl_xor(s, 2, 64);
    ss += __shfl_xor(ss, 1, 64); ss += __shfl_xor(ss, 2, 64);
    if (qt == 0){
      float mu = s * (1.f/288.f);
      float var = ss * (1.f/288.f) - mu*mu;
      smu[r] = mu; srs[r] = rsqrtf(var + 1e-5f);
    }
  }
  __syncthreads();
  int myrow = wv*16 + lq;
  float mu = smu[myrow], rs = srs[myrow];
  f32x4 a0={0,0,0,0}, a1={0,0,0,0}, a2={0,0,0,0}, a3={0,0,0,0}, a4={0,0,0,0};
  int n4c = (lq < 8) ? (64 + lq) : 71;   // clamp; cols >=72 discarded
#pragma unroll
  for (int kt = 0; kt < 9; ++kt){
    s16x8 raw = *(const s16x8*)&T2s[myrow][kt*32 + lg*8];
    f32x4 g0 = *(const f32x4*)(g  + kt*32 + lg*8);
    f32x4 g1 = *(const f32x4*)(g  + kt*32 + lg*8 + 4);
    f32x4 b0 = *(const f32x4*)(b_ + kt*32 + lg*8);
    f32x4 b1 = *(const f32x4*)(b_ + kt*32 + lg*8 + 4);
    s16x8 af;
#pragma unroll
    for (int i = 0; i < 4; ++i){
      af[i]   = (short)f2bf((bf2f((u16)raw[i])   - mu)*rs*g0[i] + b0[i]);
      af[4+i] = (short)f2bf((bf2f((u16)raw[4+i]) - mu)*rs*g1[i] + b1[i]);
    }
    s16x8 w0 = *(const s16x8*)(f1wT + (lq     )*288 + kt*32 + lg*8);
    s16x8 w1 = *(const s16x8*)(f1wT + (16 + lq)*288 + kt*32 + lg*8);
    s16x8 w2 = *(const s16x8*)(f1wT + (32 + lq)*288 + kt*32 + lg*8);
    s16x8 w3 = *(const s16x8*)(f1wT + (48 + lq)*288 + kt*32 + lg*8);
    s16x8 w4 = *(const s16x8*)(f1wT + (n4c    )*288 + kt*32 + lg*8);
    a0 = __builtin_amdgcn_mfma_f32_16x16x32_bf16(af, w0, a0, 0, 0, 0);
    a1 = __builtin_amdgcn_mfma_f32_16x16x32_bf16(af, w1, a1, 0, 0, 0);
    a2 = __builtin_amdgcn_mfma_f32_16x16x32_bf16(af, w2, a2, 0, 0, 0);
    a3 = __builtin_amdgcn_mfma_f32_16x16x32_bf16(af, w3, a3, 0, 0, 0);
    a4 = __builtin_amdgcn_mfma_f32_16x16x32_bf16(af, w4, a4, 0, 0, 0);
  }
#define H1W(ACC, F) { int n = (F)*16 + lq; if (n < 72){ float bv = f1b[n];        \
    _Pragma("unroll") for (int e = 0; e < 4; ++e)                                 \
      H1s[wv*16 + lg*4 + e][n] = f2bf(fmaxf(ACC[e] + bv, 0.f)); } }
  H1W(a0,0) H1W(a1,1) H1W(a2,2) H1W(a3,3) H1W(a4,4)
#undef H1W
  __syncthreads();
  f32x4 c[18];
#pragma unroll
  for (int f = 0; f < 18; ++f) c[f] = (f32x4){0,0,0,0};
#pragma unroll
  for (int kt = 0; kt < 3; ++kt){
    s16x8 af = *(const s16x8*)&H1s[myrow][kt*32 + lg*8];
#pragma unroll
    for (int f = 0; f < 18; ++f){
      s16x8 wf = *(const s16x8*)(f2wT + (f*16 + lq)*96 + kt*32 + lg*8);
      c[f] = __builtin_amdgcn_mfma_f32_16x16x32_bf16(af, wf, c[f], 0, 0, 0);
    }
  }
#pragma unroll
  for (int f = 0; f < 18; ++f){
    int col = f*16 + lq;
    float bv = f2b[col];
#pragma unroll
    for (int e = 0; e < 4; ++e){
      int rl = wv*16 + lg*4 + e;
      out[(row0 + rl)*288 + col] = c[f][e] + bv + bf2f(T2s[rl][col]);
    }
  }
}

// ---------------- launch ---------------------------------------------------------
extern "C" void kernel_launch(void* const* d_in, const int* in_sizes, int n_in,
                              void* d_out, int out_size, void* d_ws, size_t ws_size,
                              hipStream_t stream)
{
  const float* x   = (const float*)d_in[0];
  const float* n1g = (const float*)d_in[1];
  const float* n1b = (const float*)d_in[2];
  const float* rw  = (const float*)d_in[3];
  const float* qw  = (const float*)d_in[4];
  const float* pw  = (const float*)d_in[5];
  const float* pb  = (const float*)d_in[6];
  const float* n2g = (const float*)d_in[7];
  const float* n2b = (const float*)d_in[8];
  const float* f1w = (const float*)d_in[9];
  const float* f1b = (const float*)d_in[10];
  const float* f2w = (const float*)d_in[11];
  const float* f2b = (const float*)d_in[12];
  char* ws = (char*)d_ws;
  u16*   tb   = (u16*)(ws + 0);            // 9437184  bf16 residual t
  u16*   Qp   = (u16*)(ws + 18874368);     // 8388608  [128 bch][1024][32]
  u16*   Kp   = (u16*)(ws + 27262976);     // 8388608  swizzled
  u16*   Vtp  = (u16*)(ws + 35651584);     // 8388608  [128 bch][4 seg][32 d][256] identity-k
  u16*   aob  = (u16*)(ws + 44040192);     // 4718592
  u16*   WcT  = (u16*)(ws + 48758784);     // 432*288*2 = 248832
  u16*   pwT  = (u16*)(ws + 49007616);     // 288*160*2 = 92160
  u16*   f1wT = (u16*)(ws + 49099776);     // 72*288*2  = 41472
  u16*   f2wT = (u16*)(ws + 49141248);     // 288*96*2  = 55296
  float* out  = (float*)d_out;

  prep_w_k<<<855, 256, 0, stream>>>(rw, qw, pw, f1w, f2w, WcT, pwT, f1wT, f2wT);
  // patches + LN1 + qkv GEMM fused -> Qp/Kp/Vtp (+ Q-pad zeros, V ones row)
  hq_k<<<512, 256, 0, stream>>>(x, n1g, n1b, tb, WcT, Qp, Kp, Vtp);
  attn_k<<<512, 256, 0, stream>>>(Qp, Kp, Vtp, aob);
  // out = t2 + relu(LN(t2) @ f1w + f1b) @ f2w + f2b, t2 = t + ao @ pw + pb (fused)
  tail_k<<<256, 256, 0, stream>>>(aob, pwT, pb, tb, n2g, n2b, f1wT, f1b, f2wT, f2b, out);
}